// Round 2
// baseline (536.581 us; speedup 1.0000x reference)
//
#include <hip/hip_runtime.h>

// ---------------------------------------------------------------------------
// Attention_msa: B=1, N=2048, C=1024, H=8, d=128, SCALE=25, SIM_THRESH=0.75
// ---------------------------------------------------------------------------

#define NTOK 2048
#define CDIM 1024
#define OD   5120   // 3C (cls: q,k,v) + 2C (reg: q,k)

typedef __attribute__((ext_vector_type(8))) short bf16x8;
typedef __attribute__((ext_vector_type(4))) short s16x4;
typedef __attribute__((ext_vector_type(2))) short s16x2;
typedef __attribute__((ext_vector_type(4))) float f32x4;

#define MFMA16(a,b,c) __builtin_amdgcn_mfma_f32_16x16x32_bf16((a),(b),(c),0,0,0)

__device__ __forceinline__ short f2bf(float x){
  unsigned u = __float_as_uint(x);
  u += 0x7FFFu + ((u >> 16) & 1u);           // round-to-nearest-even
  return (short)(u >> 16);
}

// ---------------------------------------------------------------------------
// Kernel 1: QKV GEMM.  tmp[m][o] = X[m][:] . W[o][:],  o in [0,5120)
// ---------------------------------------------------------------------------
__global__ __launch_bounds__(256,2) void k_qkv(
    const float* __restrict__ xcls, const float* __restrict__ xreg,
    const float* __restrict__ Wcls, const float* __restrict__ Wreg,
    float* __restrict__ tmp)
{
  const int m0 = blockIdx.x * 64;
  const int o0 = blockIdx.y * 64;
  const float* X; const float* W; int wrow;
  if (o0 < 3072){ X = xcls; W = Wcls; wrow = o0; }
  else          { X = xreg; W = Wreg; wrow = o0 - 3072; }

  __shared__ short As[64][40];
  __shared__ short Bs[64][40];

  const int tid  = threadIdx.x;
  const int lane = tid & 63;
  const int wid  = tid >> 6;
  const int wm   = (wid >> 1) * 32;
  const int wo   = (wid & 1) * 32;
  const int fr   = lane & 15;
  const int fk   = (lane >> 4) * 8;

  f32x4 acc[2][2] = {};

  for (int k0 = 0; k0 < CDIM; k0 += 32){
    #pragma unroll
    for (int it = 0; it < 2; ++it){
      int idx = tid + it*256;
      int r = idx >> 3;
      int c = (idx & 7) << 2;
      float4 xv = *(const float4*)(X + (size_t)(m0+r)*CDIM + k0 + c);
      *(s16x4*)&As[r][c] = (s16x4){ f2bf(xv.x), f2bf(xv.y), f2bf(xv.z), f2bf(xv.w) };
      float4 wv = *(const float4*)(W + (size_t)(wrow+r)*CDIM + k0 + c);
      *(s16x4*)&Bs[r][c] = (s16x4){ f2bf(wv.x), f2bf(wv.y), f2bf(wv.z), f2bf(wv.w) };
    }
    __syncthreads();
    bf16x8 a0 = *(const bf16x8*)&As[wm      + fr][fk];
    bf16x8 a1 = *(const bf16x8*)&As[wm + 16 + fr][fk];
    bf16x8 b0 = *(const bf16x8*)&Bs[wo      + fr][fk];
    bf16x8 b1 = *(const bf16x8*)&Bs[wo + 16 + fr][fk];
    acc[0][0] = MFMA16(a0,b0,acc[0][0]);
    acc[0][1] = MFMA16(a0,b1,acc[0][1]);
    acc[1][0] = MFMA16(a1,b0,acc[1][0]);
    acc[1][1] = MFMA16(a1,b1,acc[1][1]);
    __syncthreads();
  }
  #pragma unroll
  for (int fi=0;fi<2;fi++)
    #pragma unroll
    for (int fj=0;fj<2;fj++)
      #pragma unroll
      for (int r=0;r<4;r++){
        int mm = m0 + wm + fi*16 + (lane>>4)*4 + r;
        int oo = o0 + wo + fj*16 + fr;
        tmp[(size_t)mm*OD + oo] = acc[fi][fj][r];
      }
}

// ---------------------------------------------------------------------------
// Kernel 2: per-(n,chunk,head) L2 norm + scatter to bf16 buffers.
// ---------------------------------------------------------------------------
__global__ __launch_bounds__(256,4) void k_norm(
    const float* __restrict__ tmp, float* __restrict__ out,
    short* __restrict__ qc, short* __restrict__ kc,
    short* __restrict__ qr, short* __restrict__ kr,
    short* __restrict__ vn, short* __restrict__ vb)
{
  int task = blockIdx.x*4 + (threadIdx.x>>6);
  int lane = threadIdx.x & 63;
  int n = task / 40;
  int rem = task - n*40;
  int chunk = rem >> 3;
  int h = rem & 7;
  const float* src = tmp + (size_t)n*OD + (chunk<<10) + h*128;
  float2 v = *(const float2*)(src + lane*2);
  float ss = v.x*v.x + v.y*v.y;
  #pragma unroll
  for (int m=1;m<64;m<<=1) ss += __shfl_xor(ss, m);
  float rn = 1.0f / sqrtf(ss);
  size_t base = ((size_t)h*NTOK + n)*128 + lane*2;
  s16x2 nv = { f2bf(v.x*rn), f2bf(v.y*rn) };
  switch(chunk){
    case 0: *(s16x2*)&qc[base] = nv; break;
    case 1: *(s16x2*)&kc[base] = nv; break;
    case 3: *(s16x2*)&qr[base] = nv; break;
    case 4: *(s16x2*)&kr[base] = nv; break;
    default: {
      *(s16x2*)&vn[base] = nv;
      *(s16x2*)&vb[base] = (s16x2){ f2bf(v.x), f2bf(v.y) };
      *(float2*)&out[(size_t)n*2048 + 1024 + h*128 + lane*2] = v;
      break;
    }
  }
}

// ---------------------------------------------------------------------------
// Kernel 3: transpose raw v (bf16) [h][n][d] -> vT [h][d][n]
// ---------------------------------------------------------------------------
__global__ __launch_bounds__(256,4) void k_vT(
    const short* __restrict__ vb, short* __restrict__ vT)
{
  int b = blockIdx.x;
  int h  = b >> 6;
  int nt = (b >> 1) & 31;
  int dt = b & 1;
  __shared__ short t[64][72];
  int tid = threadIdx.x;
  int r  = tid >> 2;
  int c0 = (tid & 3) << 4;
  #pragma unroll
  for (int u=0;u<2;u++){
    bf16x8 val = *(const bf16x8*)&vb[((size_t)h*NTOK + nt*64 + r)*128 + dt*64 + c0 + u*8];
    #pragma unroll
    for (int e=0;e<8;e++) t[r][c0+u*8+e] = val[e];
  }
  __syncthreads();
  #pragma unroll
  for (int u=0;u<2;u++){
    bf16x8 o;
    #pragma unroll
    for (int e=0;e<8;e++) o[e] = t[c0+u*8+e][r];
    *(bf16x8*)&vT[((size_t)h*128 + dt*64 + r)*NTOK + nt*64 + c0 + u*8] = o;
  }
}

// ---------------------------------------------------------------------------
// Kernel 4: attention pass (1-wave blocks for occupancy; no __syncthreads).
// ---------------------------------------------------------------------------
__global__ __launch_bounds__(64,2) void k_attn(
    const short* __restrict__ qc, const short* __restrict__ kc,
    const short* __restrict__ qr, const short* __restrict__ kr,
    const short* __restrict__ vT,
    const float* __restrict__ csc, const float* __restrict__ fsc,
    float* __restrict__ s_cls, float* __restrict__ s_reg,
    float* __restrict__ out)
{
  const int h    = blockIdx.y;
  const int lane = threadIdx.x & 63;
  const int i0   = blockIdx.x * 16;
  const int fr   = lane & 15;
  const int fk   = (lane >> 4) * 8;
  const size_t hN = (size_t)h * NTOK;

  __shared__ __align__(16) short Et[2][16][32];
  short (*Ec)[32] = Et[0];
  short (*Er)[32] = Et[1];

  bf16x8 aq[4], ar[4];
  #pragma unroll
  for (int kk=0;kk<4;kk++){
    aq[kk] = *(const bf16x8*)&qc[(hN + i0 + fr)*128 + kk*32 + fk];
    ar[kk] = *(const bf16x8*)&qr[(hN + i0 + fr)*128 + kk*32 + fk];
  }
  const int rowbase = i0 + ((lane>>4)<<2);
  float sci[4], sfi[4];
  #pragma unroll
  for (int r=0;r<4;r++){ sci[r]=csc[rowbase+r]; sfi[r]=fsc[rowbase+r]; }

  f32x4 Uc[8] = {}; f32x4 Ur[8] = {};
  float pc[4] = {0,0,0,0}, pr[4] = {0,0,0,0};

  for (int j0 = 0; j0 < NTOK; j0 += 32){
    f32x4 Sc[2] = {}; f32x4 Sr[2] = {};
    #pragma unroll
    for (int f=0; f<2; f++){
      #pragma unroll
      for (int kk=0;kk<4;kk++){
        bf16x8 b  = *(const bf16x8*)&kc[(hN + j0 + f*16 + fr)*128 + kk*32 + fk];
        Sc[f] = MFMA16(aq[kk], b, Sc[f]);
        bf16x8 b2 = *(const bf16x8*)&kr[(hN + j0 + f*16 + fr)*128 + kk*32 + fk];
        Sr[f] = MFMA16(ar[kk], b2, Sr[f]);
      }
    }
    #pragma unroll
    for (int f=0; f<2; f++){
      int col = j0 + f*16 + fr;
      float sjc = csc[col], sjf = fsc[col];
      #pragma unroll
      for (int r=0;r<4;r++){
        float ec = (sjc > sci[r]-0.1f) ? __expf(Sc[f][r]*(25.0f*sjc)) : 1.0f;
        float er = (sjf > sfi[r]-0.1f) ? __expf(Sr[f][r]*(25.0f*sjf)) : 1.0f;
        pc[r] += ec; pr[r] += er;
        Ec[(lane>>4)*4+r][f*16+fr] = f2bf(ec);
        Er[(lane>>4)*4+r][f*16+fr] = f2bf(er);
      }
    }
    bf16x8 ea = *(const bf16x8*)&Ec[fr][fk];
    bf16x8 eb = *(const bf16x8*)&Er[fr][fk];
    #pragma unroll
    for (int c=0;c<8;c++){
      bf16x8 bv = *(const bf16x8*)&vT[((size_t)h*128 + c*16 + fr)*NTOK + j0 + fk];
      Uc[c] = MFMA16(ea, bv, Uc[c]);
      Ur[c] = MFMA16(eb, bv, Ur[c]);
    }
  }
  #pragma unroll
  for (int m=1;m<16;m<<=1){
    #pragma unroll
    for (int r=0;r<4;r++){ pc[r]+=__shfl_xor(pc[r],m); pr[r]+=__shfl_xor(pr[r],m); }
  }
  if (fr == 0){
    #pragma unroll
    for (int r=0;r<4;r++){ s_cls[hN+rowbase+r]=pc[r]; s_reg[hN+rowbase+r]=pr[r]; }
  }
  float ipc[4], ipr[4];
  #pragma unroll
  for (int r=0;r<4;r++){ ipc[r]=1.0f/pc[r]; ipr[r]=1.0f/pr[r]; }
  #pragma unroll
  for (int c=0;c<8;c++)
    #pragma unroll
    for (int r=0;r<4;r++){
      float val = 0.5f*(Uc[c][r]*ipc[r] + Ur[c][r]*ipr[r]);
      out[(size_t)(rowbase+r)*2048 + h*128 + c*16 + fr] = val;
    }
}

// ---------------------------------------------------------------------------
// Kernel 5: sim_attn. Block tile 128i x 64j, 4 waves (each 32i x 64j).
// B tiles (kc,kr rows j0..j0+64) staged per head in LDS, FRAGMENT-MAJOR
// layout: [stream][frag=js*4+kk][lane][8] -> ds_read is lane-linear 1KB
// (conflict-free) and staging global loads are cacheline-coalesced.
// A fragments (q rows) kept in registers per head.
// ---------------------------------------------------------------------------
__global__ __launch_bounds__(256,2) void k_sim(
    const short* __restrict__ qc, const short* __restrict__ kc,
    const short* __restrict__ qr, const short* __restrict__ kr,
    const float* __restrict__ csc, const float* __restrict__ fsc,
    const float* __restrict__ s_cls, const float* __restrict__ s_reg,
    float* __restrict__ out)
{
  const int tid  = threadIdx.x;
  const int lane = tid & 63;
  const int w    = tid >> 6;
  const int i0w  = blockIdx.x * 128 + w * 32;
  const int j0   = blockIdx.y * 64;
  const int fr   = lane & 15;
  const int fk   = (lane >> 4) * 8;

  __shared__ __align__(16) short Bsh[2][16][64][8];   // 32 KiB

  float sjc[4], sjf[4];
  #pragma unroll
  for (int js=0;js<4;js++){ sjc[js]=csc[j0+js*16+fr]; sjf[js]=fsc[j0+js*16+fr]; }
  int rowb[2]; float sci[2][4], sfi[2][4];
  #pragma unroll
  for (int ri=0;ri<2;ri++){
    rowb[ri] = i0w + ri*16 + ((lane>>4)<<2);
    #pragma unroll
    for (int r=0;r<4;r++){ sci[ri][r]=csc[rowb[ri]+r]; sfi[ri][r]=fsc[rowb[ri]+r]; }
  }

  f32x4 sim[2][4] = {};

  for (int h=0; h<8; ++h){
    const size_t hb = (size_t)h * NTOK;
    bf16x8 aq[2][4], ar[2][4];
    #pragma unroll
    for (int ri=0;ri<2;ri++)
      #pragma unroll
      for (int kk=0;kk<4;kk++){
        aq[ri][kk] = *(const bf16x8*)&qc[(hb + i0w + ri*16 + fr)*128 + kk*32 + fk];
        ar[ri][kk] = *(const bf16x8*)&qr[(hb + i0w + ri*16 + fr)*128 + kk*32 + fk];
      }
    float iscl[2][4], isrl[2][4];
    #pragma unroll
    for (int ri=0;ri<2;ri++)
      #pragma unroll
      for (int r=0;r<4;r++){
        iscl[ri][r] = 1.0f/s_cls[hb + rowb[ri] + r];
        isrl[ri][r] = 1.0f/s_reg[hb + rowb[ri] + r];
      }
    __syncthreads();
    #pragma unroll
    for (int it=0; it<8; ++it){
      int slot = it*256 + tid;          // 2048 slots of 16B
      int str  = slot >> 10;
      int frag = (slot >> 6) & 15;
      int l    = slot & 63;
      int r    = (frag >> 2)*16 + (l & 15);
      int c    = (frag & 3)*32 + (l >> 4)*8;
      const short* g = (str ? kr : kc) + (hb + j0 + r)*128 + c;
      *(bf16x8*)&Bsh[str][frag][l][0] = *(const bf16x8*)g;
    }
    __syncthreads();
    #pragma unroll
    for (int js=0; js<4; ++js){
      bf16x8 bc[4], br[4];
      #pragma unroll
      for (int kk=0;kk<4;kk++){
        bc[kk] = *(const bf16x8*)&Bsh[0][js*4+kk][lane][0];
        br[kk] = *(const bf16x8*)&Bsh[1][js*4+kk][lane][0];
      }
      #pragma unroll
      for (int ri=0;ri<2;ri++){
        f32x4 Sc = {}; f32x4 Sr = {};
        #pragma unroll
        for (int kk=0;kk<4;kk++){
          Sc = MFMA16(aq[ri][kk], bc[kk], Sc);
          Sr = MFMA16(ar[ri][kk], br[kk], Sr);
        }
        #pragma unroll
        for (int r=0;r<4;r++){
          float ec = (sjc[js] > sci[ri][r]-0.1f) ? __expf(Sc[r]*(25.0f*sjc[js])) : 1.0f;
          float er = (sjf[js] > sfi[ri][r]-0.1f) ? __expf(Sr[r]*(25.0f*sjf[js])) : 1.0f;
          sim[ri][js][r] += ec*iscl[ri][r] + er*isrl[ri][r];
        }
      }
    }
  }
  #pragma unroll
  for (int ri=0;ri<2;ri++)
    #pragma unroll
    for (int js=0;js<4;js++)
      #pragma unroll
      for (int r=0;r<4;r++)
        out[4194304ull + (size_t)(rowb[ri]+r)*2048 + j0 + js*16 + fr]
            = sim[ri][js][r] * 0.0625f;
}

// ---------------------------------------------------------------------------
// Kernel 5b: raw = Vn . Vn^T over full C=1024 (sum over heads); mask = raw>6.
// Same frag-major staged-GEMM structure, single stream.
// ---------------------------------------------------------------------------
__global__ __launch_bounds__(256,4) void k_raw(
    const short* __restrict__ vn, unsigned char* __restrict__ mask)
{
  const int tid  = threadIdx.x;
  const int lane = tid & 63;
  const int w    = tid >> 6;
  const int i0w  = blockIdx.x * 128 + w * 32;
  const int j0   = blockIdx.y * 64;
  const int fr   = lane & 15;
  const int fk   = (lane >> 4) * 8;

  __shared__ __align__(16) short Bsh[16][64][8];   // 16 KiB

  f32x4 raw[2][4] = {};

  for (int cc=0; cc<8; ++cc){
    const size_t hb = (size_t)cc * NTOK;
    bf16x8 av[2][4];
    #pragma unroll
    for (int ri=0;ri<2;ri++)
      #pragma unroll
      for (int kk=0;kk<4;kk++)
        av[ri][kk] = *(const bf16x8*)&vn[(hb + i0w + ri*16 + fr)*128 + kk*32 + fk];
    __syncthreads();
    #pragma unroll
    for (int it=0; it<4; ++it){
      int slot = it*256 + tid;          // 1024 slots of 16B
      int frag = (slot >> 6) & 15;
      int l    = slot & 63;
      int r    = (frag >> 2)*16 + (l & 15);
      int c    = (frag & 3)*32 + (l >> 4)*8;
      *(bf16x8*)&Bsh[frag][l][0] = *(const bf16x8*)&vn[(hb + j0 + r)*128 + c];
    }
    __syncthreads();
    #pragma unroll
    for (int js=0; js<4; ++js){
      bf16x8 bv[4];
      #pragma unroll
      for (int kk=0;kk<4;kk++) bv[kk] = *(const bf16x8*)&Bsh[js*4+kk][lane][0];
      #pragma unroll
      for (int ri=0;ri<2;ri++)
        #pragma unroll
        for (int kk=0;kk<4;kk++)
          raw[ri][js] = MFMA16(av[ri][kk], bv[kk], raw[ri][js]);
    }
  }
  const int rb0 = i0w + ((lane>>4)<<2);
  #pragma unroll
  for (int ri=0;ri<2;ri++)
    #pragma unroll
    for (int js=0;js<4;js++)
      #pragma unroll
      for (int r=0;r<4;r++)
        mask[(size_t)(rb0 + ri*16 + r)*2048 + j0 + js*16 + fr]
            = raw[ri][js][r] > 6.0f ? 1 : 0;
}

// ---------------------------------------------------------------------------
// Kernel 6: final masked renorm (in place on sim half of out).
// ---------------------------------------------------------------------------
__global__ __launch_bounds__(256,4) void k_final(
    float* __restrict__ out, const unsigned char* __restrict__ mask)
{
  int row  = blockIdx.x*4 + (threadIdx.x>>6);
  int lane = threadIdx.x & 63;
  float* sr = out + 4194304ull + (size_t)row*2048;
  const unsigned char* mr = mask + (size_t)row*2048;
  float v[32];
  float sum2 = 0.0f;
  #pragma unroll
  for (int c=0;c<32;c++){
    float e = __expf(sr[c*64 + lane]);
    v[c] = (mr[c*64 + lane] != 0) ? e : 0.0f;
    sum2 += v[c];
  }
  #pragma unroll
  for (int m=1;m<64;m<<=1) sum2 += __shfl_xor(sum2, m);
  float inv = 1.0f / sum2;
  #pragma unroll
  for (int c=0;c<32;c++) sr[c*64 + lane] = v[c]*inv;
}

// ---------------------------------------------------------------------------
extern "C" void kernel_launch(void* const* d_in, const int* in_sizes, int n_in,
                              void* d_out, int out_size, void* d_ws, size_t ws_size,
                              hipStream_t stream)
{
  const float* xcls = (const float*)d_in[0];
  const float* xreg = (const float*)d_in[1];
  const float* csc  = (const float*)d_in[2];
  const float* fsc  = (const float*)d_in[3];
  const float* Wc   = (const float*)d_in[4];
  const float* Wr   = (const float*)d_in[5];
  float* out = (float*)d_out;

  char* ws = (char*)d_ws;
  float* tmp          = (float*)ws;
  unsigned char* mask = (unsigned char*)ws;          // overlays tmp (dead after k_norm)
  float* s_cls        = (float*)(ws + 8u*1024*1024);
  float* s_reg        = (float*)(ws + 8u*1024*1024 + 64*1024);
  short* qc = (short*)(ws + 41943040ull);
  short* kc = qc + 2097152;
  short* qr = kc + 2097152;
  short* kr = qr + 2097152;
  short* vn = kr + 2097152;
  short* vb = vn + 2097152;
  short* vT = vb + 2097152;

  k_qkv  <<<dim3(32,80), 256, 0, stream>>>(xcls, xreg, Wc, Wr, tmp);
  k_norm <<<20480,       256, 0, stream>>>(tmp, out, qc, kc, qr, kr, vn, vb);
  k_vT   <<<512,         256, 0, stream>>>(vb, vT);
  k_attn <<<dim3(128,8), 64,  0, stream>>>(qc, kc, qr, kr, vT, csc, fsc, s_cls, s_reg, out);
  k_raw  <<<dim3(16,32), 256, 0, stream>>>(vn, mask);
  k_sim  <<<dim3(16,32), 256, 0, stream>>>(qc, kc, qr, kr, csc, fsc, s_cls, s_reg, out);
  k_final<<<512,         256, 0, stream>>>(out, mask);
}

// Round 3
// 524.275 us; speedup vs baseline: 1.0235x; 1.0235x over previous
//
#include <hip/hip_runtime.h>

// ---------------------------------------------------------------------------
// Attention_msa: B=1, N=2048, C=1024, H=8, d=128, SCALE=25, SIM_THRESH=0.75
// ---------------------------------------------------------------------------

#define NTOK 2048
#define CDIM 1024
#define OD   5120   // 3C (cls: q,k,v) + 2C (reg: q,k)

typedef __attribute__((ext_vector_type(8))) short bf16x8;
typedef __attribute__((ext_vector_type(4))) short s16x4;
typedef __attribute__((ext_vector_type(2))) short s16x2;
typedef __attribute__((ext_vector_type(4))) float f32x4;

#define MFMA16(a,b,c) __builtin_amdgcn_mfma_f32_16x16x32_bf16((a),(b),(c),0,0,0)

__device__ __forceinline__ short f2bf(float x){
  unsigned u = __float_as_uint(x);
  u += 0x7FFFu + ((u >> 16) & 1u);           // round-to-nearest-even
  return (short)(u >> 16);
}

__device__ __forceinline__ void atomAddF(float* p, float v){
  unsafeAtomicAdd(p, v);                     // global_atomic_add_f32 (gfx90a+)
}

// ---------------------------------------------------------------------------
// Kernel 1: QKV GEMM.  tmp[m][o] = X[m][:] . W[o][:],  o in [0,5120)
// ---------------------------------------------------------------------------
__global__ __launch_bounds__(256,2) void k_qkv(
    const float* __restrict__ xcls, const float* __restrict__ xreg,
    const float* __restrict__ Wcls, const float* __restrict__ Wreg,
    float* __restrict__ tmp)
{
  const int m0 = blockIdx.x * 64;
  const int o0 = blockIdx.y * 64;
  const float* X; const float* W; int wrow;
  if (o0 < 3072){ X = xcls; W = Wcls; wrow = o0; }
  else          { X = xreg; W = Wreg; wrow = o0 - 3072; }

  __shared__ short As[64][40];
  __shared__ short Bs[64][40];

  const int tid  = threadIdx.x;
  const int lane = tid & 63;
  const int wid  = tid >> 6;
  const int wm   = (wid >> 1) * 32;
  const int wo   = (wid & 1) * 32;
  const int fr   = lane & 15;
  const int fk   = (lane >> 4) * 8;

  f32x4 acc[2][2] = {};

  for (int k0 = 0; k0 < CDIM; k0 += 32){
    #pragma unroll
    for (int it = 0; it < 2; ++it){
      int idx = tid + it*256;
      int r = idx >> 3;
      int c = (idx & 7) << 2;
      float4 xv = *(const float4*)(X + (size_t)(m0+r)*CDIM + k0 + c);
      *(s16x4*)&As[r][c] = (s16x4){ f2bf(xv.x), f2bf(xv.y), f2bf(xv.z), f2bf(xv.w) };
      float4 wv = *(const float4*)(W + (size_t)(wrow+r)*CDIM + k0 + c);
      *(s16x4*)&Bs[r][c] = (s16x4){ f2bf(wv.x), f2bf(wv.y), f2bf(wv.z), f2bf(wv.w) };
    }
    __syncthreads();
    bf16x8 a0 = *(const bf16x8*)&As[wm      + fr][fk];
    bf16x8 a1 = *(const bf16x8*)&As[wm + 16 + fr][fk];
    bf16x8 b0 = *(const bf16x8*)&Bs[wo      + fr][fk];
    bf16x8 b1 = *(const bf16x8*)&Bs[wo + 16 + fr][fk];
    acc[0][0] = MFMA16(a0,b0,acc[0][0]);
    acc[0][1] = MFMA16(a0,b1,acc[0][1]);
    acc[1][0] = MFMA16(a1,b0,acc[1][0]);
    acc[1][1] = MFMA16(a1,b1,acc[1][1]);
    __syncthreads();
  }
  #pragma unroll
  for (int fi=0;fi<2;fi++)
    #pragma unroll
    for (int fj=0;fj<2;fj++)
      #pragma unroll
      for (int r=0;r<4;r++){
        int mm = m0 + wm + fi*16 + (lane>>4)*4 + r;
        int oo = o0 + wo + fj*16 + fr;
        tmp[(size_t)mm*OD + oo] = acc[fi][fj][r];
      }
}

// ---------------------------------------------------------------------------
// Kernel 2: per-(n,chunk,head) L2 norm + scatter to bf16 buffers.
// ---------------------------------------------------------------------------
__global__ __launch_bounds__(256,4) void k_norm(
    const float* __restrict__ tmp, float* __restrict__ out,
    short* __restrict__ qc, short* __restrict__ kc,
    short* __restrict__ qr, short* __restrict__ kr,
    short* __restrict__ vn, short* __restrict__ vb)
{
  int task = blockIdx.x*4 + (threadIdx.x>>6);
  int lane = threadIdx.x & 63;
  int n = task / 40;
  int rem = task - n*40;
  int chunk = rem >> 3;
  int h = rem & 7;
  const float* src = tmp + (size_t)n*OD + (chunk<<10) + h*128;
  float2 v = *(const float2*)(src + lane*2);
  float ss = v.x*v.x + v.y*v.y;
  #pragma unroll
  for (int m=1;m<64;m<<=1) ss += __shfl_xor(ss, m);
  float rn = 1.0f / sqrtf(ss);
  size_t base = ((size_t)h*NTOK + n)*128 + lane*2;
  s16x2 nv = { f2bf(v.x*rn), f2bf(v.y*rn) };
  switch(chunk){
    case 0: *(s16x2*)&qc[base] = nv; break;
    case 1: *(s16x2*)&kc[base] = nv; break;
    case 3: *(s16x2*)&qr[base] = nv; break;
    case 4: *(s16x2*)&kr[base] = nv; break;
    default: {
      *(s16x2*)&vn[base] = nv;
      *(s16x2*)&vb[base] = (s16x2){ f2bf(v.x), f2bf(v.y) };
      *(float2*)&out[(size_t)n*2048 + 1024 + h*128 + lane*2] = v;
      break;
    }
  }
}

// ---------------------------------------------------------------------------
// Kernel 3: transpose raw v (bf16) [h][n][d] -> vT [h][d][n]
// ---------------------------------------------------------------------------
__global__ __launch_bounds__(256,4) void k_vT(
    const short* __restrict__ vb, short* __restrict__ vT)
{
  int b = blockIdx.x;
  int h  = b >> 6;
  int nt = (b >> 1) & 31;
  int dt = b & 1;
  __shared__ short t[64][72];
  int tid = threadIdx.x;
  int r  = tid >> 2;
  int c0 = (tid & 3) << 4;
  #pragma unroll
  for (int u=0;u<2;u++){
    bf16x8 val = *(const bf16x8*)&vb[((size_t)h*NTOK + nt*64 + r)*128 + dt*64 + c0 + u*8];
    #pragma unroll
    for (int e=0;e<8;e++) t[r][c0+u*8+e] = val[e];
  }
  __syncthreads();
  #pragma unroll
  for (int u=0;u<2;u++){
    bf16x8 o;
    #pragma unroll
    for (int e=0;e<8;e++) o[e] = t[c0+u*8+e][r];
    *(bf16x8*)&vT[((size_t)h*128 + dt*64 + r)*NTOK + nt*64 + c0 + u*8] = o;
  }
}

// ---------------------------------------------------------------------------
// Kernel 4: attention, j-split partial pass. Grid (128 rowtiles, 8 heads,
// 4 j-splits); 1 wave/block; partial U and row sums accumulated with HW f32
// atomics into zeroed scratch. vT fragments prefetched at loop top so PV
// loads overlap the QK->exp chain.
// ---------------------------------------------------------------------------
#define JSPLIT 4
#define JLEN  (NTOK/JSPLIT)

__global__ __launch_bounds__(64,4) void k_attn(
    const short* __restrict__ qc, const short* __restrict__ kc,
    const short* __restrict__ qr, const short* __restrict__ kr,
    const short* __restrict__ vT,
    const float* __restrict__ csc, const float* __restrict__ fsc,
    float* __restrict__ s_cls, float* __restrict__ s_reg,
    float* __restrict__ Uca, float* __restrict__ Ura)
{
  const int h    = blockIdx.y;
  const int lane = threadIdx.x & 63;
  const int i0   = blockIdx.x * 16;
  const int j0lo = blockIdx.z * JLEN;
  const int fr   = lane & 15;
  const int fk   = (lane >> 4) * 8;
  const size_t hN = (size_t)h * NTOK;

  __shared__ __align__(16) short Et[2][16][32];
  short (*Ec)[32] = Et[0];
  short (*Er)[32] = Et[1];

  bf16x8 aq[4], ar[4];
  #pragma unroll
  for (int kk=0;kk<4;kk++){
    aq[kk] = *(const bf16x8*)&qc[(hN + i0 + fr)*128 + kk*32 + fk];
    ar[kk] = *(const bf16x8*)&qr[(hN + i0 + fr)*128 + kk*32 + fk];
  }
  const int rowbase = i0 + ((lane>>4)<<2);
  float sci[4], sfi[4];
  #pragma unroll
  for (int r=0;r<4;r++){ sci[r]=csc[rowbase+r]; sfi[r]=fsc[rowbase+r]; }

  f32x4 Uc[8] = {}; f32x4 Ur[8] = {};
  float pc[4] = {0,0,0,0}, pr[4] = {0,0,0,0};

  for (int j0 = j0lo; j0 < j0lo + JLEN; j0 += 32){
    // prefetch PV B-operands (independent of the QK chain)
    bf16x8 bv[8];
    #pragma unroll
    for (int c=0;c<8;c++)
      bv[c] = *(const bf16x8*)&vT[((size_t)h*128 + c*16 + fr)*NTOK + j0 + fk];

    f32x4 Sc[2] = {}; f32x4 Sr[2] = {};
    #pragma unroll
    for (int f=0; f<2; f++){
      #pragma unroll
      for (int kk=0;kk<4;kk++){
        bf16x8 b  = *(const bf16x8*)&kc[(hN + j0 + f*16 + fr)*128 + kk*32 + fk];
        Sc[f] = MFMA16(aq[kk], b, Sc[f]);
        bf16x8 b2 = *(const bf16x8*)&kr[(hN + j0 + f*16 + fr)*128 + kk*32 + fk];
        Sr[f] = MFMA16(ar[kk], b2, Sr[f]);
      }
    }
    #pragma unroll
    for (int f=0; f<2; f++){
      int col = j0 + f*16 + fr;
      float sjc = csc[col], sjf = fsc[col];
      #pragma unroll
      for (int r=0;r<4;r++){
        float ec = (sjc > sci[r]-0.1f) ? __expf(Sc[f][r]*(25.0f*sjc)) : 1.0f;
        float er = (sjf > sfi[r]-0.1f) ? __expf(Sr[f][r]*(25.0f*sjf)) : 1.0f;
        pc[r] += ec; pr[r] += er;
        Ec[(lane>>4)*4+r][f*16+fr] = f2bf(ec);
        Er[(lane>>4)*4+r][f*16+fr] = f2bf(er);
      }
    }
    bf16x8 ea = *(const bf16x8*)&Ec[fr][fk];
    bf16x8 eb = *(const bf16x8*)&Er[fr][fk];
    #pragma unroll
    for (int c=0;c<8;c++){
      Uc[c] = MFMA16(ea, bv[c], Uc[c]);
      Ur[c] = MFMA16(eb, bv[c], Ur[c]);
    }
  }
  #pragma unroll
  for (int m=1;m<16;m<<=1){
    #pragma unroll
    for (int r=0;r<4;r++){ pc[r]+=__shfl_xor(pc[r],m); pr[r]+=__shfl_xor(pr[r],m); }
  }
  if (fr == 0){
    #pragma unroll
    for (int r=0;r<4;r++){
      atomAddF(&s_cls[hN+rowbase+r], pc[r]);
      atomAddF(&s_reg[hN+rowbase+r], pr[r]);
    }
  }
  #pragma unroll
  for (int c=0;c<8;c++)
    #pragma unroll
    for (int r=0;r<4;r++){
      size_t idx = (hN + rowbase + r)*128 + c*16 + fr;
      atomAddF(&Uca[idx], Uc[c][r]);
      atomAddF(&Ura[idx], Ur[c][r]);
    }
}

// ---------------------------------------------------------------------------
// Kernel 4b: combine partials -> x half of out = 0.5*(Uc/sc + Ur/sr)
// ---------------------------------------------------------------------------
__global__ __launch_bounds__(256,8) void k_attn_fin(
    const float* __restrict__ Uca, const float* __restrict__ Ura,
    const float* __restrict__ s_cls, const float* __restrict__ s_reg,
    float* __restrict__ out)
{
  int task = blockIdx.x*4 + (threadIdx.x>>6);   // h*2048 + row
  int lane = threadIdx.x & 63;
  int h = task >> 11;
  int row = task & 2047;
  size_t b = (size_t)task*128 + lane*2;
  float2 uc = *(const float2*)(Uca + b);
  float2 ur = *(const float2*)(Ura + b);
  float isc = 0.5f/s_cls[task];
  float isr = 0.5f/s_reg[task];
  float2 o = { uc.x*isc + ur.x*isr, uc.y*isc + ur.y*isr };
  *(float2*)&out[(size_t)row*2048 + h*128 + lane*2] = o;
}

// ---------------------------------------------------------------------------
// Kernel 5: sim_attn. Block tile 128i x 64j, 4 waves; frag-major LDS staging.
// ---------------------------------------------------------------------------
__global__ __launch_bounds__(256,2) void k_sim(
    const short* __restrict__ qc, const short* __restrict__ kc,
    const short* __restrict__ qr, const short* __restrict__ kr,
    const float* __restrict__ csc, const float* __restrict__ fsc,
    const float* __restrict__ s_cls, const float* __restrict__ s_reg,
    float* __restrict__ out)
{
  const int tid  = threadIdx.x;
  const int lane = tid & 63;
  const int w    = tid >> 6;
  const int i0w  = blockIdx.x * 128 + w * 32;
  const int j0   = blockIdx.y * 64;
  const int fr   = lane & 15;
  const int fk   = (lane >> 4) * 8;

  __shared__ __align__(16) short Bsh[2][16][64][8];   // 32 KiB

  float sjc[4], sjf[4];
  #pragma unroll
  for (int js=0;js<4;js++){ sjc[js]=csc[j0+js*16+fr]; sjf[js]=fsc[j0+js*16+fr]; }
  int rowb[2]; float sci[2][4], sfi[2][4];
  #pragma unroll
  for (int ri=0;ri<2;ri++){
    rowb[ri] = i0w + ri*16 + ((lane>>4)<<2);
    #pragma unroll
    for (int r=0;r<4;r++){ sci[ri][r]=csc[rowb[ri]+r]; sfi[ri][r]=fsc[rowb[ri]+r]; }
  }

  f32x4 sim[2][4] = {};

  for (int h=0; h<8; ++h){
    const size_t hb = (size_t)h * NTOK;
    bf16x8 aq[2][4], ar[2][4];
    #pragma unroll
    for (int ri=0;ri<2;ri++)
      #pragma unroll
      for (int kk=0;kk<4;kk++){
        aq[ri][kk] = *(const bf16x8*)&qc[(hb + i0w + ri*16 + fr)*128 + kk*32 + fk];
        ar[ri][kk] = *(const bf16x8*)&qr[(hb + i0w + ri*16 + fr)*128 + kk*32 + fk];
      }
    float iscl[2][4], isrl[2][4];
    #pragma unroll
    for (int ri=0;ri<2;ri++)
      #pragma unroll
      for (int r=0;r<4;r++){
        iscl[ri][r] = 1.0f/s_cls[hb + rowb[ri] + r];
        isrl[ri][r] = 1.0f/s_reg[hb + rowb[ri] + r];
      }
    __syncthreads();
    #pragma unroll
    for (int it=0; it<8; ++it){
      int slot = it*256 + tid;
      int str  = slot >> 10;
      int frag = (slot >> 6) & 15;
      int l    = slot & 63;
      int r    = (frag >> 2)*16 + (l & 15);
      int c    = (frag & 3)*32 + (l >> 4)*8;
      const short* g = (str ? kr : kc) + (hb + j0 + r)*128 + c;
      *(bf16x8*)&Bsh[str][frag][l][0] = *(const bf16x8*)g;
    }
    __syncthreads();
    #pragma unroll
    for (int js=0; js<4; ++js){
      bf16x8 bc[4], br[4];
      #pragma unroll
      for (int kk=0;kk<4;kk++){
        bc[kk] = *(const bf16x8*)&Bsh[0][js*4+kk][lane][0];
        br[kk] = *(const bf16x8*)&Bsh[1][js*4+kk][lane][0];
      }
      #pragma unroll
      for (int ri=0;ri<2;ri++){
        f32x4 Sc = {}; f32x4 Sr = {};
        #pragma unroll
        for (int kk=0;kk<4;kk++){
          Sc = MFMA16(aq[ri][kk], bc[kk], Sc);
          Sr = MFMA16(ar[ri][kk], br[kk], Sr);
        }
        #pragma unroll
        for (int r=0;r<4;r++){
          float ec = (sjc[js] > sci[ri][r]-0.1f) ? __expf(Sc[r]*(25.0f*sjc[js])) : 1.0f;
          float er = (sjf[js] > sfi[ri][r]-0.1f) ? __expf(Sr[r]*(25.0f*sjf[js])) : 1.0f;
          sim[ri][js][r] += ec*iscl[ri][r] + er*isrl[ri][r];
        }
      }
    }
  }
  #pragma unroll
  for (int ri=0;ri<2;ri++)
    #pragma unroll
    for (int js=0;js<4;js++)
      #pragma unroll
      for (int r=0;r<4;r++)
        out[4194304ull + (size_t)(rowb[ri]+r)*2048 + j0 + js*16 + fr]
            = sim[ri][js][r] * 0.0625f;
}

// ---------------------------------------------------------------------------
// Kernel 5b: raw = Vn . Vn^T over full C=1024; mask = raw>6.
// ---------------------------------------------------------------------------
__global__ __launch_bounds__(256,4) void k_raw(
    const short* __restrict__ vn, unsigned char* __restrict__ mask)
{
  const int tid  = threadIdx.x;
  const int lane = tid & 63;
  const int w    = tid >> 6;
  const int i0w  = blockIdx.x * 128 + w * 32;
  const int j0   = blockIdx.y * 64;
  const int fr   = lane & 15;
  const int fk   = (lane >> 4) * 8;

  __shared__ __align__(16) short Bsh[16][64][8];   // 16 KiB

  f32x4 raw[2][4] = {};

  for (int cc=0; cc<8; ++cc){
    const size_t hb = (size_t)cc * NTOK;
    bf16x8 av[2][4];
    #pragma unroll
    for (int ri=0;ri<2;ri++)
      #pragma unroll
      for (int kk=0;kk<4;kk++)
        av[ri][kk] = *(const bf16x8*)&vn[(hb + i0w + ri*16 + fr)*128 + kk*32 + fk];
    __syncthreads();
    #pragma unroll
    for (int it=0; it<4; ++it){
      int slot = it*256 + tid;
      int frag = (slot >> 6) & 15;
      int l    = slot & 63;
      int r    = (frag >> 2)*16 + (l & 15);
      int c    = (frag & 3)*32 + (l >> 4)*8;
      *(bf16x8*)&Bsh[frag][l][0] = *(const bf16x8*)&vn[(hb + j0 + r)*128 + c];
    }
    __syncthreads();
    #pragma unroll
    for (int js=0; js<4; ++js){
      bf16x8 bv[4];
      #pragma unroll
      for (int kk=0;kk<4;kk++) bv[kk] = *(const bf16x8*)&Bsh[js*4+kk][lane][0];
      #pragma unroll
      for (int ri=0;ri<2;ri++)
        #pragma unroll
        for (int kk=0;kk<4;kk++)
          raw[ri][js] = MFMA16(av[ri][kk], bv[kk], raw[ri][js]);
    }
  }
  const int rb0 = i0w + ((lane>>4)<<2);
  #pragma unroll
  for (int ri=0;ri<2;ri++)
    #pragma unroll
    for (int js=0;js<4;js++)
      #pragma unroll
      for (int r=0;r<4;r++)
        mask[(size_t)(rb0 + ri*16 + r)*2048 + j0 + js*16 + fr]
            = raw[ri][js][r] > 6.0f ? 1 : 0;
}

// ---------------------------------------------------------------------------
// Kernel 6: final masked renorm (in place on sim half of out).
// ---------------------------------------------------------------------------
__global__ __launch_bounds__(256,4) void k_final(
    float* __restrict__ out, const unsigned char* __restrict__ mask)
{
  int row  = blockIdx.x*4 + (threadIdx.x>>6);
  int lane = threadIdx.x & 63;
  float* sr = out + 4194304ull + (size_t)row*2048;
  const unsigned char* mr = mask + (size_t)row*2048;
  float v[32];
  float sum2 = 0.0f;
  #pragma unroll
  for (int c=0;c<32;c++){
    float e = __expf(sr[c*64 + lane]);
    v[c] = (mr[c*64 + lane] != 0) ? e : 0.0f;
    sum2 += v[c];
  }
  #pragma unroll
  for (int m=1;m<64;m<<=1) sum2 += __shfl_xor(sum2, m);
  float inv = 1.0f / sum2;
  #pragma unroll
  for (int c=0;c<32;c++) sr[c*64 + lane] = v[c]*inv;
}

// ---------------------------------------------------------------------------
extern "C" void kernel_launch(void* const* d_in, const int* in_sizes, int n_in,
                              void* d_out, int out_size, void* d_ws, size_t ws_size,
                              hipStream_t stream)
{
  const float* xcls = (const float*)d_in[0];
  const float* xreg = (const float*)d_in[1];
  const float* csc  = (const float*)d_in[2];
  const float* fsc  = (const float*)d_in[3];
  const float* Wc   = (const float*)d_in[4];
  const float* Wr   = (const float*)d_in[5];
  float* out = (float*)d_out;

  char* ws = (char*)d_ws;
  // tmp f32 [0, 41.94MB) -- dead after k_norm; overlays:
  //   mask   @ 0        (4 MB)
  //   s_cls  @ 8MB      (64 KB)   \
  //   s_reg  @ 8MB+64K  (64 KB)    | zeroed together (16.9 MB memset)
  //   Uca    @ 8MB+128K (8.39 MB)  |
  //   Ura    @ +8.39MB  (8.39 MB) /   ends at ~25 MB < 41.94 MB
  float* tmp          = (float*)ws;
  unsigned char* mask = (unsigned char*)ws;
  char* accbase       = ws + 8u*1024*1024;
  float* s_cls        = (float*)(accbase);
  float* s_reg        = (float*)(accbase + 65536);
  float* Uca          = (float*)(accbase + 131072);
  float* Ura          = (float*)(accbase + 131072 + 8388608);
  size_t acc_bytes    = 131072 + 2*8388608;
  short* qc = (short*)(ws + 41943040ull);
  short* kc = qc + 2097152;
  short* qr = kc + 2097152;
  short* kr = qr + 2097152;
  short* vn = kr + 2097152;
  short* vb = vn + 2097152;
  short* vT = vb + 2097152;

  k_qkv  <<<dim3(32,80), 256, 0, stream>>>(xcls, xreg, Wc, Wr, tmp);
  k_norm <<<20480,       256, 0, stream>>>(tmp, out, qc, kc, qr, kr, vn, vb);
  k_vT   <<<512,         256, 0, stream>>>(vb, vT);
  hipMemsetAsync(accbase, 0, acc_bytes, stream);
  k_attn <<<dim3(128,8,JSPLIT), 64, 0, stream>>>(qc, kc, qr, kr, vT, csc, fsc,
                                                 s_cls, s_reg, Uca, Ura);
  k_attn_fin <<<4096,    256, 0, stream>>>(Uca, Ura, s_cls, s_reg, out);
  k_raw  <<<dim3(16,32), 256, 0, stream>>>(vn, mask);
  k_sim  <<<dim3(16,32), 256, 0, stream>>>(qc, kc, qr, kr, csc, fsc, s_cls, s_reg, out);
  k_final<<<512,         256, 0, stream>>>(out, mask);
}

// Round 4
// 405.352 us; speedup vs baseline: 1.3237x; 1.2934x over previous
//
#include <hip/hip_runtime.h>

// ---------------------------------------------------------------------------
// Attention_msa: B=1, N=2048, C=1024, H=8, d=128, SCALE=25, SIM_THRESH=0.75
// ---------------------------------------------------------------------------

#define NTOK 2048
#define CDIM 1024
#define OD   5120   // 3C (cls: q,k,v) + 2C (reg: q,k)

typedef __attribute__((ext_vector_type(8))) short bf16x8;
typedef __attribute__((ext_vector_type(4))) short s16x4;
typedef __attribute__((ext_vector_type(2))) short s16x2;
typedef __attribute__((ext_vector_type(4))) float f32x4;

#define MFMA16(a,b,c) __builtin_amdgcn_mfma_f32_16x16x32_bf16((a),(b),(c),0,0,0)

__device__ __forceinline__ short f2bf(float x){
  unsigned u = __float_as_uint(x);
  u += 0x7FFFu + ((u >> 16) & 1u);           // round-to-nearest-even
  return (short)(u >> 16);
}

__device__ __forceinline__ void atomAddF(float* p, float v){
  unsafeAtomicAdd(p, v);                     // global_atomic_add_f32
}

// ---------------------------------------------------------------------------
// Kernel 1: QKV GEMM.  tmp[m][o] = X[m][:] . W[o][:],  o in [0,5120)
// ---------------------------------------------------------------------------
__global__ __launch_bounds__(256,2) void k_qkv(
    const float* __restrict__ xcls, const float* __restrict__ xreg,
    const float* __restrict__ Wcls, const float* __restrict__ Wreg,
    float* __restrict__ tmp)
{
  const int m0 = blockIdx.x * 64;
  const int o0 = blockIdx.y * 64;
  const float* X; const float* W; int wrow;
  if (o0 < 3072){ X = xcls; W = Wcls; wrow = o0; }
  else          { X = xreg; W = Wreg; wrow = o0 - 3072; }

  __shared__ short As[64][40];
  __shared__ short Bs[64][40];

  const int tid  = threadIdx.x;
  const int lane = tid & 63;
  const int wid  = tid >> 6;
  const int wm   = (wid >> 1) * 32;
  const int wo   = (wid & 1) * 32;
  const int fr   = lane & 15;
  const int fk   = (lane >> 4) * 8;

  f32x4 acc[2][2] = {};

  for (int k0 = 0; k0 < CDIM; k0 += 32){
    #pragma unroll
    for (int it = 0; it < 2; ++it){
      int idx = tid + it*256;
      int r = idx >> 3;
      int c = (idx & 7) << 2;
      float4 xv = *(const float4*)(X + (size_t)(m0+r)*CDIM + k0 + c);
      *(s16x4*)&As[r][c] = (s16x4){ f2bf(xv.x), f2bf(xv.y), f2bf(xv.z), f2bf(xv.w) };
      float4 wv = *(const float4*)(W + (size_t)(wrow+r)*CDIM + k0 + c);
      *(s16x4*)&Bs[r][c] = (s16x4){ f2bf(wv.x), f2bf(wv.y), f2bf(wv.z), f2bf(wv.w) };
    }
    __syncthreads();
    bf16x8 a0 = *(const bf16x8*)&As[wm      + fr][fk];
    bf16x8 a1 = *(const bf16x8*)&As[wm + 16 + fr][fk];
    bf16x8 b0 = *(const bf16x8*)&Bs[wo      + fr][fk];
    bf16x8 b1 = *(const bf16x8*)&Bs[wo + 16 + fr][fk];
    acc[0][0] = MFMA16(a0,b0,acc[0][0]);
    acc[0][1] = MFMA16(a0,b1,acc[0][1]);
    acc[1][0] = MFMA16(a1,b0,acc[1][0]);
    acc[1][1] = MFMA16(a1,b1,acc[1][1]);
    __syncthreads();
  }
  #pragma unroll
  for (int fi=0;fi<2;fi++)
    #pragma unroll
    for (int fj=0;fj<2;fj++)
      #pragma unroll
      for (int r=0;r<4;r++){
        int mm = m0 + wm + fi*16 + (lane>>4)*4 + r;
        int oo = o0 + wo + fj*16 + fr;
        tmp[(size_t)mm*OD + oo] = acc[fi][fj][r];
      }
}

// ---------------------------------------------------------------------------
// Kernel 2: per-(n,chunk,head) L2 norm + scatter to bf16 buffers.
// ---------------------------------------------------------------------------
__global__ __launch_bounds__(256,4) void k_norm(
    const float* __restrict__ tmp, float* __restrict__ out,
    short* __restrict__ qc, short* __restrict__ kc,
    short* __restrict__ qr, short* __restrict__ kr,
    short* __restrict__ vn, short* __restrict__ vb)
{
  int task = blockIdx.x*4 + (threadIdx.x>>6);
  int lane = threadIdx.x & 63;
  int n = task / 40;
  int rem = task - n*40;
  int chunk = rem >> 3;
  int h = rem & 7;
  const float* src = tmp + (size_t)n*OD + (chunk<<10) + h*128;
  float2 v = *(const float2*)(src + lane*2);
  float ss = v.x*v.x + v.y*v.y;
  #pragma unroll
  for (int m=1;m<64;m<<=1) ss += __shfl_xor(ss, m);
  float rn = 1.0f / sqrtf(ss);
  size_t base = ((size_t)h*NTOK + n)*128 + lane*2;
  s16x2 nv = { f2bf(v.x*rn), f2bf(v.y*rn) };
  switch(chunk){
    case 0: *(s16x2*)&qc[base] = nv; break;
    case 1: *(s16x2*)&kc[base] = nv; break;
    case 3: *(s16x2*)&qr[base] = nv; break;
    case 4: *(s16x2*)&kr[base] = nv; break;
    default: {
      *(s16x2*)&vn[base] = nv;
      *(s16x2*)&vb[base] = (s16x2){ f2bf(v.x), f2bf(v.y) };
      *(float2*)&out[(size_t)n*2048 + 1024 + h*128 + lane*2] = v;
      break;
    }
  }
}

// ---------------------------------------------------------------------------
// Kernel 3: transpose raw v (bf16) [h][n][d] -> vT [h][d][n]
// ---------------------------------------------------------------------------
__global__ __launch_bounds__(256,4) void k_vT(
    const short* __restrict__ vb, short* __restrict__ vT)
{
  int b = blockIdx.x;
  int h  = b >> 6;
  int nt = (b >> 1) & 31;
  int dt = b & 1;
  __shared__ short t[64][72];
  int tid = threadIdx.x;
  int r  = tid >> 2;
  int c0 = (tid & 3) << 4;
  #pragma unroll
  for (int u=0;u<2;u++){
    bf16x8 val = *(const bf16x8*)&vb[((size_t)h*NTOK + nt*64 + r)*128 + dt*64 + c0 + u*8];
    #pragma unroll
    for (int e=0;e<8;e++) t[r][c0+u*8+e] = val[e];
  }
  __syncthreads();
  #pragma unroll
  for (int u=0;u<2;u++){
    bf16x8 o;
    #pragma unroll
    for (int e=0;e<8;e++) o[e] = t[c0+u*8+e][r];
    *(bf16x8*)&vT[((size_t)h*128 + dt*64 + r)*NTOK + nt*64 + c0 + u*8] = o;
  }
}

// ---------------------------------------------------------------------------
// Kernel 4: attention partial pass, LDS-staged.
// Grid (16 i-blocks, 8 heads, 8 = 4 j-splits x 2 streams). Block = 4 waves,
// each wave owns 32 rows (block 128). Per 64-j tile: stage K (frag-major,
// 16KB) + vT (frag-major, 16KB) cooperatively; QK MFMA from LDS; exp; E
// relayout via per-wave frag-major LDS (16KB); PV MFMA. Partials accumulated
// with f32 atomics (4 contributors per cell).
// ---------------------------------------------------------------------------
#define JLEN 512

__global__ __launch_bounds__(256,3) void k_attn(
    const short* __restrict__ qc, const short* __restrict__ kc,
    const short* __restrict__ qr, const short* __restrict__ kr,
    const short* __restrict__ vT,
    const float* __restrict__ csc, const float* __restrict__ fsc,
    float* __restrict__ s_cls, float* __restrict__ s_reg,
    float* __restrict__ Uca, float* __restrict__ Ura)
{
  const int tid = threadIdx.x;
  const int l   = tid & 63;
  const int w   = tid >> 6;
  const int h   = blockIdx.y;
  const int s   = blockIdx.z & 1;
  const int js  = blockIdx.z >> 1;
  const int iw  = blockIdx.x * 128 + w * 32;   // wave's first row
  const int fr  = l & 15;
  const int fk8 = (l >> 4) * 8;
  const size_t hN = (size_t)h * NTOK;

  const short* Qp = s ? qr : qc;
  const short* Kp = s ? kr : kc;
  const float* sc = s ? fsc : csc;
  float* Uacc     = s ? Ura : Uca;
  float* ssum     = s ? s_reg : s_cls;

  __shared__ __align__(16) short Kbuf[4][4][64][8];     // [jf][kk][lane][8] 16KB
  __shared__ __align__(16) short Vbuf[8][2][64][8];     // [df][ks][lane][8] 16KB
  __shared__ __align__(16) short Ebuf[4][2][2][64][8];  // [w][if][ks][l'][8] 16KB

  bf16x8 aq[2][4];
  #pragma unroll
  for (int i2=0;i2<2;i2++)
    #pragma unroll
    for (int kk=0;kk<4;kk++)
      aq[i2][kk] = *(const bf16x8*)&Qp[(hN + iw + i2*16 + fr)*128 + kk*32 + fk8];

  float sci[2][4];
  #pragma unroll
  for (int i2=0;i2<2;i2++)
    #pragma unroll
    for (int r=0;r<4;r++)
      sci[i2][r] = sc[iw + i2*16 + (l>>4)*4 + r];

  f32x4 U[2][8] = {};
  float p[2][4] = {};

  const int ebyte = l & 7;
  const int ehi   = (l >> 3) & 1;

  for (int jt = 0; jt < JLEN/64; ++jt){
    const int j0 = js*JLEN + jt*64;
    __syncthreads();
    // ---- cooperative staging: 32 frags of 1KB; wave w takes 8 ----
    #pragma unroll
    for (int q8=0; q8<8; ++q8){
      int t = w*8 + q8;
      if (t < 16){
        int jf = t >> 2, kk = t & 3;
        bf16x8 val = *(const bf16x8*)&Kp[(hN + j0 + jf*16 + fr)*128 + kk*32 + fk8];
        *(bf16x8*)&Kbuf[jf][kk][l][0] = val;
      } else {
        int u = t - 16, df = u >> 1, ks = u & 1;
        bf16x8 val = *(const bf16x8*)&vT[((size_t)h*128 + df*16 + fr)*2048 + j0 + ks*32 + fk8];
        *(bf16x8*)&Vbuf[df][ks][l][0] = val;
      }
    }
    __syncthreads();
    // ---- QK + exp + E-relayout ----
    #pragma unroll
    for (int jf=0; jf<4; ++jf){
      f32x4 S0 = {}; f32x4 S1 = {};
      #pragma unroll
      for (int kk=0; kk<4; ++kk){
        bf16x8 b = *(const bf16x8*)&Kbuf[jf][kk][l][0];
        S0 = MFMA16(aq[0][kk], b, S0);
        S1 = MFMA16(aq[1][kk], b, S1);
      }
      float sj = sc[j0 + jf*16 + fr];
      float sj25 = 25.0f * sj;
      const int ks  = jf >> 1;
      const int sub = ((jf & 1) << 1) | ehi;
      #pragma unroll
      for (int r=0;r<4;r++){
        float e0 = (sj > sci[0][r]-0.1f) ? __expf(S0[r]*sj25) : 1.0f;
        float e1 = (sj > sci[1][r]-0.1f) ? __expf(S1[r]*sj25) : 1.0f;
        p[0][r] += e0; p[1][r] += e1;
        int lrow = (l>>4)*4 + r + (sub<<4);
        Ebuf[w][0][ks][lrow][ebyte] = f2bf(e0);
        Ebuf[w][1][ks][lrow][ebyte] = f2bf(e1);
      }
    }
    // ---- PV ----
    #pragma unroll
    for (int ks=0; ks<2; ++ks){
      bf16x8 ef0 = *(const bf16x8*)&Ebuf[w][0][ks][l][0];
      bf16x8 ef1 = *(const bf16x8*)&Ebuf[w][1][ks][l][0];
      #pragma unroll
      for (int df=0; df<8; ++df){
        bf16x8 bv = *(const bf16x8*)&Vbuf[df][ks][l][0];
        U[0][df] = MFMA16(ef0, bv, U[0][df]);
        U[1][df] = MFMA16(ef1, bv, U[1][df]);
      }
    }
  }
  // ---- row sums (reduce over lane bits 0..3) + atomics ----
  #pragma unroll
  for (int m=1;m<16;m<<=1)
    #pragma unroll
    for (int i2=0;i2<2;i2++)
      #pragma unroll
      for (int r=0;r<4;r++) p[i2][r] += __shfl_xor(p[i2][r], m);
  if (fr == 0){
    #pragma unroll
    for (int i2=0;i2<2;i2++)
      #pragma unroll
      for (int r=0;r<4;r++)
        atomAddF(&ssum[hN + iw + i2*16 + (l>>4)*4 + r], p[i2][r]);
  }
  #pragma unroll
  for (int i2=0;i2<2;i2++)
    #pragma unroll
    for (int df=0;df<8;df++)
      #pragma unroll
      for (int r=0;r<4;r++)
        atomAddF(&Uacc[(hN + iw + i2*16 + (l>>4)*4 + r)*128 + df*16 + fr],
                 U[i2][df][r]);
}

// ---------------------------------------------------------------------------
// Kernel 4b: combine partials -> x half of out = 0.5*(Uc/sc + Ur/sr)
// ---------------------------------------------------------------------------
__global__ __launch_bounds__(256,8) void k_attn_fin(
    const float* __restrict__ Uca, const float* __restrict__ Ura,
    const float* __restrict__ s_cls, const float* __restrict__ s_reg,
    float* __restrict__ out)
{
  int task = blockIdx.x*4 + (threadIdx.x>>6);   // h*2048 + row
  int lane = threadIdx.x & 63;
  int h = task >> 11;
  int row = task & 2047;
  size_t b = (size_t)task*128 + lane*2;
  float2 uc = *(const float2*)(Uca + b);
  float2 ur = *(const float2*)(Ura + b);
  float isc = 0.5f/s_cls[task];
  float isr = 0.5f/s_reg[task];
  float2 o = { uc.x*isc + ur.x*isr, uc.y*isc + ur.y*isr };
  *(float2*)&out[(size_t)row*2048 + h*128 + lane*2] = o;
}

// ---------------------------------------------------------------------------
// Kernel 5: sim_attn. Block tile 128i x 64j, 4 waves; frag-major LDS staging.
// ---------------------------------------------------------------------------
__global__ __launch_bounds__(256,2) void k_sim(
    const short* __restrict__ qc, const short* __restrict__ kc,
    const short* __restrict__ qr, const short* __restrict__ kr,
    const float* __restrict__ csc, const float* __restrict__ fsc,
    const float* __restrict__ s_cls, const float* __restrict__ s_reg,
    float* __restrict__ out)
{
  const int tid  = threadIdx.x;
  const int lane = tid & 63;
  const int w    = tid >> 6;
  const int i0w  = blockIdx.x * 128 + w * 32;
  const int j0   = blockIdx.y * 64;
  const int fr   = lane & 15;
  const int fk   = (lane >> 4) * 8;

  __shared__ __align__(16) short Bsh[2][16][64][8];   // 32 KiB

  float sjc[4], sjf[4];
  #pragma unroll
  for (int js=0;js<4;js++){ sjc[js]=csc[j0+js*16+fr]; sjf[js]=fsc[j0+js*16+fr]; }
  int rowb[2]; float sci[2][4], sfi[2][4];
  #pragma unroll
  for (int ri=0;ri<2;ri++){
    rowb[ri] = i0w + ri*16 + ((lane>>4)<<2);
    #pragma unroll
    for (int r=0;r<4;r++){ sci[ri][r]=csc[rowb[ri]+r]; sfi[ri][r]=fsc[rowb[ri]+r]; }
  }

  f32x4 sim[2][4] = {};

  for (int h=0; h<8; ++h){
    const size_t hb = (size_t)h * NTOK;
    bf16x8 aq[2][4], ar[2][4];
    #pragma unroll
    for (int ri=0;ri<2;ri++)
      #pragma unroll
      for (int kk=0;kk<4;kk++){
        aq[ri][kk] = *(const bf16x8*)&qc[(hb + i0w + ri*16 + fr)*128 + kk*32 + fk];
        ar[ri][kk] = *(const bf16x8*)&qr[(hb + i0w + ri*16 + fr)*128 + kk*32 + fk];
      }
    float iscl[2][4], isrl[2][4];
    #pragma unroll
    for (int ri=0;ri<2;ri++)
      #pragma unroll
      for (int r=0;r<4;r++){
        iscl[ri][r] = 1.0f/s_cls[hb + rowb[ri] + r];
        isrl[ri][r] = 1.0f/s_reg[hb + rowb[ri] + r];
      }
    __syncthreads();
    #pragma unroll
    for (int it=0; it<8; ++it){
      int slot = it*256 + tid;
      int str  = slot >> 10;
      int frag = (slot >> 6) & 15;
      int l    = slot & 63;
      int r    = (frag >> 2)*16 + (l & 15);
      int c    = (frag & 3)*32 + (l >> 4)*8;
      const short* g = (str ? kr : kc) + (hb + j0 + r)*128 + c;
      *(bf16x8*)&Bsh[str][frag][l][0] = *(const bf16x8*)g;
    }
    __syncthreads();
    #pragma unroll
    for (int js=0; js<4; ++js){
      bf16x8 bc[4], br[4];
      #pragma unroll
      for (int kk=0;kk<4;kk++){
        bc[kk] = *(const bf16x8*)&Bsh[0][js*4+kk][lane][0];
        br[kk] = *(const bf16x8*)&Bsh[1][js*4+kk][lane][0];
      }
      #pragma unroll
      for (int ri=0;ri<2;ri++){
        f32x4 Sc = {}; f32x4 Sr = {};
        #pragma unroll
        for (int kk=0;kk<4;kk++){
          Sc = MFMA16(aq[ri][kk], bc[kk], Sc);
          Sr = MFMA16(ar[ri][kk], br[kk], Sr);
        }
        #pragma unroll
        for (int r=0;r<4;r++){
          float ec = (sjc[js] > sci[ri][r]-0.1f) ? __expf(Sc[r]*(25.0f*sjc[js])) : 1.0f;
          float er = (sjf[js] > sfi[ri][r]-0.1f) ? __expf(Sr[r]*(25.0f*sjf[js])) : 1.0f;
          sim[ri][js][r] += ec*iscl[ri][r] + er*isrl[ri][r];
        }
      }
    }
  }
  #pragma unroll
  for (int ri=0;ri<2;ri++)
    #pragma unroll
    for (int js=0;js<4;js++)
      #pragma unroll
      for (int r=0;r<4;r++)
        out[4194304ull + (size_t)(rowb[ri]+r)*2048 + j0 + js*16 + fr]
            = sim[ri][js][r] * 0.0625f;
}

// ---------------------------------------------------------------------------
// Kernel 5b: raw = Vn . Vn^T over full C=1024; mask = raw>6.
// ---------------------------------------------------------------------------
__global__ __launch_bounds__(256,4) void k_raw(
    const short* __restrict__ vn, unsigned char* __restrict__ mask)
{
  const int tid  = threadIdx.x;
  const int lane = tid & 63;
  const int w    = tid >> 6;
  const int i0w  = blockIdx.x * 128 + w * 32;
  const int j0   = blockIdx.y * 64;
  const int fr   = lane & 15;
  const int fk   = (lane >> 4) * 8;

  __shared__ __align__(16) short Bsh[16][64][8];   // 16 KiB

  f32x4 raw[2][4] = {};

  for (int cc=0; cc<8; ++cc){
    const size_t hb = (size_t)cc * NTOK;
    bf16x8 av[2][4];
    #pragma unroll
    for (int ri=0;ri<2;ri++)
      #pragma unroll
      for (int kk=0;kk<4;kk++)
        av[ri][kk] = *(const bf16x8*)&vn[(hb + i0w + ri*16 + fr)*128 + kk*32 + fk];
    __syncthreads();
    #pragma unroll
    for (int it=0; it<4; ++it){
      int slot = it*256 + tid;
      int frag = (slot >> 6) & 15;
      int l    = slot & 63;
      int r    = (frag >> 2)*16 + (l & 15);
      int c    = (frag & 3)*32 + (l >> 4)*8;
      *(bf16x8*)&Bsh[frag][l][0] = *(const bf16x8*)&vn[(hb + j0 + r)*128 + c];
    }
    __syncthreads();
    #pragma unroll
    for (int js=0; js<4; ++js){
      bf16x8 bv[4];
      #pragma unroll
      for (int kk=0;kk<4;kk++) bv[kk] = *(const bf16x8*)&Bsh[js*4+kk][lane][0];
      #pragma unroll
      for (int ri=0;ri<2;ri++)
        #pragma unroll
        for (int kk=0;kk<4;kk++)
          raw[ri][js] = MFMA16(av[ri][kk], bv[kk], raw[ri][js]);
    }
  }
  const int rb0 = i0w + ((lane>>4)<<2);
  #pragma unroll
  for (int ri=0;ri<2;ri++)
    #pragma unroll
    for (int js=0;js<4;js++)
      #pragma unroll
      for (int r=0;r<4;r++)
        mask[(size_t)(rb0 + ri*16 + r)*2048 + j0 + js*16 + fr]
            = raw[ri][js][r] > 6.0f ? 1 : 0;
}

// ---------------------------------------------------------------------------
// Kernel 6: final masked renorm (in place on sim half of out).
// ---------------------------------------------------------------------------
__global__ __launch_bounds__(256,4) void k_final(
    float* __restrict__ out, const unsigned char* __restrict__ mask)
{
  int row  = blockIdx.x*4 + (threadIdx.x>>6);
  int lane = threadIdx.x & 63;
  float* sr = out + 4194304ull + (size_t)row*2048;
  const unsigned char* mr = mask + (size_t)row*2048;
  float v[32];
  float sum2 = 0.0f;
  #pragma unroll
  for (int c=0;c<32;c++){
    float e = __expf(sr[c*64 + lane]);
    v[c] = (mr[c*64 + lane] != 0) ? e : 0.0f;
    sum2 += v[c];
  }
  #pragma unroll
  for (int m=1;m<64;m<<=1) sum2 += __shfl_xor(sum2, m);
  float inv = 1.0f / sum2;
  #pragma unroll
  for (int c=0;c<32;c++) sr[c*64 + lane] = v[c]*inv;
}

// ---------------------------------------------------------------------------
extern "C" void kernel_launch(void* const* d_in, const int* in_sizes, int n_in,
                              void* d_out, int out_size, void* d_ws, size_t ws_size,
                              hipStream_t stream)
{
  const float* xcls = (const float*)d_in[0];
  const float* xreg = (const float*)d_in[1];
  const float* csc  = (const float*)d_in[2];
  const float* fsc  = (const float*)d_in[3];
  const float* Wc   = (const float*)d_in[4];
  const float* Wr   = (const float*)d_in[5];
  float* out = (float*)d_out;

  char* ws = (char*)d_ws;
  // tmp f32 [0, 41.94MB) -- dead after k_norm; overlays:
  //   mask @0 (4MB); s_cls/s_reg @8MB (128KB); Uca/Ura @8MB+128K (16.8MB)
  float* tmp          = (float*)ws;
  unsigned char* mask = (unsigned char*)ws;
  char* accbase       = ws + 8u*1024*1024;
  float* s_cls        = (float*)(accbase);
  float* s_reg        = (float*)(accbase + 65536);
  float* Uca          = (float*)(accbase + 131072);
  float* Ura          = (float*)(accbase + 131072 + 8388608);
  size_t acc_bytes    = 131072 + 2*8388608;
  short* qc = (short*)(ws + 41943040ull);
  short* kc = qc + 2097152;
  short* qr = kc + 2097152;
  short* kr = qr + 2097152;
  short* vn = kr + 2097152;
  short* vb = vn + 2097152;
  short* vT = vb + 2097152;

  k_qkv  <<<dim3(32,80), 256, 0, stream>>>(xcls, xreg, Wc, Wr, tmp);
  k_norm <<<20480,       256, 0, stream>>>(tmp, out, qc, kc, qr, kr, vn, vb);
  k_vT   <<<512,         256, 0, stream>>>(vb, vT);
  hipMemsetAsync(accbase, 0, acc_bytes, stream);
  k_attn <<<dim3(16,8,8), 256, 0, stream>>>(qc, kc, qr, kr, vT, csc, fsc,
                                            s_cls, s_reg, Uca, Ura);
  k_attn_fin <<<4096,    256, 0, stream>>>(Uca, Ura, s_cls, s_reg, out);
  k_raw  <<<dim3(16,32), 256, 0, stream>>>(vn, mask);
  k_sim  <<<dim3(16,32), 256, 0, stream>>>(qc, kc, qr, kr, csc, fsc, s_cls, s_reg, out);
  k_final<<<512,         256, 0, stream>>>(out, mask);
}

// Round 5
// 400.906 us; speedup vs baseline: 1.3384x; 1.0111x over previous
//
#include <hip/hip_runtime.h>

// ---------------------------------------------------------------------------
// Attention_msa: B=1, N=2048, C=1024, H=8, d=128, SCALE=25, SIM_THRESH=0.75
// ---------------------------------------------------------------------------

#define NTOK 2048
#define CDIM 1024
#define OD   5120   // 3C (cls: q,k,v) + 2C (reg: q,k)

typedef __attribute__((ext_vector_type(8))) short bf16x8;
typedef __attribute__((ext_vector_type(4))) short s16x4;
typedef __attribute__((ext_vector_type(2))) short s16x2;
typedef __attribute__((ext_vector_type(4))) float f32x4;

#define MFMA16(a,b,c) __builtin_amdgcn_mfma_f32_16x16x32_bf16((a),(b),(c),0,0,0)

__device__ __forceinline__ short f2bf(float x){
  unsigned u = __float_as_uint(x);
  u += 0x7FFFu + ((u >> 16) & 1u);           // round-to-nearest-even
  return (short)(u >> 16);
}

__device__ __forceinline__ void atomAddF(float* p, float v){
  unsafeAtomicAdd(p, v);                     // global_atomic_add_f32
}

// async global->LDS, 16B per lane; LDS dest = uniform base + lane*16
__device__ __forceinline__ void gld16(const short* g, short* l){
  __builtin_amdgcn_global_load_lds(
      (const __attribute__((address_space(1))) unsigned int*)g,
      (__attribute__((address_space(3))) unsigned int*)l, 16, 0, 0);
}

// ---------------------------------------------------------------------------
// Kernel 1: QKV GEMM.  tmp[m][o] = X[m][:] . W[o][:],  o in [0,5120)
// ---------------------------------------------------------------------------
__global__ __launch_bounds__(256,2) void k_qkv(
    const float* __restrict__ xcls, const float* __restrict__ xreg,
    const float* __restrict__ Wcls, const float* __restrict__ Wreg,
    float* __restrict__ tmp)
{
  const int m0 = blockIdx.x * 64;
  const int o0 = blockIdx.y * 64;
  const float* X; const float* W; int wrow;
  if (o0 < 3072){ X = xcls; W = Wcls; wrow = o0; }
  else          { X = xreg; W = Wreg; wrow = o0 - 3072; }

  __shared__ short As[64][40];
  __shared__ short Bs[64][40];

  const int tid  = threadIdx.x;
  const int lane = tid & 63;
  const int wid  = tid >> 6;
  const int wm   = (wid >> 1) * 32;
  const int wo   = (wid & 1) * 32;
  const int fr   = lane & 15;
  const int fk   = (lane >> 4) * 8;

  f32x4 acc[2][2] = {};

  for (int k0 = 0; k0 < CDIM; k0 += 32){
    #pragma unroll
    for (int it = 0; it < 2; ++it){
      int idx = tid + it*256;
      int r = idx >> 3;
      int c = (idx & 7) << 2;
      float4 xv = *(const float4*)(X + (size_t)(m0+r)*CDIM + k0 + c);
      *(s16x4*)&As[r][c] = (s16x4){ f2bf(xv.x), f2bf(xv.y), f2bf(xv.z), f2bf(xv.w) };
      float4 wv = *(const float4*)(W + (size_t)(wrow+r)*CDIM + k0 + c);
      *(s16x4*)&Bs[r][c] = (s16x4){ f2bf(wv.x), f2bf(wv.y), f2bf(wv.z), f2bf(wv.w) };
    }
    __syncthreads();
    bf16x8 a0 = *(const bf16x8*)&As[wm      + fr][fk];
    bf16x8 a1 = *(const bf16x8*)&As[wm + 16 + fr][fk];
    bf16x8 b0 = *(const bf16x8*)&Bs[wo      + fr][fk];
    bf16x8 b1 = *(const bf16x8*)&Bs[wo + 16 + fr][fk];
    acc[0][0] = MFMA16(a0,b0,acc[0][0]);
    acc[0][1] = MFMA16(a0,b1,acc[0][1]);
    acc[1][0] = MFMA16(a1,b0,acc[1][0]);
    acc[1][1] = MFMA16(a1,b1,acc[1][1]);
    __syncthreads();
  }
  #pragma unroll
  for (int fi=0;fi<2;fi++)
    #pragma unroll
    for (int fj=0;fj<2;fj++)
      #pragma unroll
      for (int r=0;r<4;r++){
        int mm = m0 + wm + fi*16 + (lane>>4)*4 + r;
        int oo = o0 + wo + fj*16 + fr;
        tmp[(size_t)mm*OD + oo] = acc[fi][fj][r];
      }
}

// ---------------------------------------------------------------------------
// Kernel 2: per-(n,chunk,head) L2 norm + scatter to bf16 buffers.
// ---------------------------------------------------------------------------
__global__ __launch_bounds__(256,4) void k_norm(
    const float* __restrict__ tmp, float* __restrict__ out,
    short* __restrict__ qc, short* __restrict__ kc,
    short* __restrict__ qr, short* __restrict__ kr,
    short* __restrict__ vn, short* __restrict__ vb)
{
  int task = blockIdx.x*4 + (threadIdx.x>>6);
  int lane = threadIdx.x & 63;
  int n = task / 40;
  int rem = task - n*40;
  int chunk = rem >> 3;
  int h = rem & 7;
  const float* src = tmp + (size_t)n*OD + (chunk<<10) + h*128;
  float2 v = *(const float2*)(src + lane*2);
  float ss = v.x*v.x + v.y*v.y;
  #pragma unroll
  for (int m=1;m<64;m<<=1) ss += __shfl_xor(ss, m);
  float rn = 1.0f / sqrtf(ss);
  size_t base = ((size_t)h*NTOK + n)*128 + lane*2;
  s16x2 nv = { f2bf(v.x*rn), f2bf(v.y*rn) };
  switch(chunk){
    case 0: *(s16x2*)&qc[base] = nv; break;
    case 1: *(s16x2*)&kc[base] = nv; break;
    case 3: *(s16x2*)&qr[base] = nv; break;
    case 4: *(s16x2*)&kr[base] = nv; break;
    default: {
      *(s16x2*)&vn[base] = nv;
      *(s16x2*)&vb[base] = (s16x2){ f2bf(v.x), f2bf(v.y) };
      *(float2*)&out[(size_t)n*2048 + 1024 + h*128 + lane*2] = v;
      break;
    }
  }
}

// ---------------------------------------------------------------------------
// Kernel 3: transpose raw v (bf16) [h][n][d] -> vT [h][d][n]
// ---------------------------------------------------------------------------
__global__ __launch_bounds__(256,4) void k_vT(
    const short* __restrict__ vb, short* __restrict__ vT)
{
  int b = blockIdx.x;
  int h  = b >> 6;
  int nt = (b >> 1) & 31;
  int dt = b & 1;
  __shared__ short t[64][72];
  int tid = threadIdx.x;
  int r  = tid >> 2;
  int c0 = (tid & 3) << 4;
  #pragma unroll
  for (int u=0;u<2;u++){
    bf16x8 val = *(const bf16x8*)&vb[((size_t)h*NTOK + nt*64 + r)*128 + dt*64 + c0 + u*8];
    #pragma unroll
    for (int e=0;e<8;e++) t[r][c0+u*8+e] = val[e];
  }
  __syncthreads();
  #pragma unroll
  for (int u=0;u<2;u++){
    bf16x8 o;
    #pragma unroll
    for (int e=0;e<8;e++) o[e] = t[c0+u*8+e][r];
    *(bf16x8*)&vT[((size_t)h*128 + dt*64 + r)*NTOK + nt*64 + c0 + u*8] = o;
  }
}

// ---------------------------------------------------------------------------
// Kernel 4: attention partial pass, LDS-staged, double-buffered, XCD-swizzled.
// 1-D grid of 1024 decoded so the 16 i-blocks sharing a (head, jsplit, stream)
// K/V slice are consecutive on ONE XCD (L2 reuse). Per 64-j tile: stage next
// tile's K (frag-major) + vT (frag-major) via global_load_lds into buf^1,
// compute current tile from buf (QK MFMA -> exp -> E relayout -> PV MFMA),
// barrier drains. Partials accumulated with f32 atomics (4 contributors).
// ---------------------------------------------------------------------------
#define JLEN 512

__global__ __launch_bounds__(256,2) void k_attn(
    const short* __restrict__ qc, const short* __restrict__ kc,
    const short* __restrict__ qr, const short* __restrict__ kr,
    const short* __restrict__ vT,
    const float* __restrict__ csc, const float* __restrict__ fsc,
    float* __restrict__ s_cls, float* __restrict__ s_reg,
    float* __restrict__ Uca, float* __restrict__ Ura)
{
  const int tid = threadIdx.x;
  const int l   = tid & 63;
  const int w   = tid >> 6;
  // XCD-grouped swizzle: xcd = L%8; 8 groups of 16 i-blocks per XCD.
  const int L    = blockIdx.x;
  const int xcd  = L & 7;
  const int slot = L >> 3;
  const int g    = xcd + ((slot >> 4) << 3);   // 64 groups = (h,z)
  const int ib   = slot & 15;
  const int h    = g >> 3;
  const int z    = g & 7;
  const int s    = z & 1;
  const int js   = z >> 1;

  const int iw  = ib * 128 + w * 32;           // wave's first row
  const int fr  = l & 15;
  const int fk8 = (l >> 4) * 8;
  const size_t hN = (size_t)h * NTOK;
  const size_t hD = (size_t)h * 128;

  const short* Qp = s ? qr : qc;
  const short* Kp = s ? kr : kc;
  const float* sc = s ? fsc : csc;
  float* Uacc     = s ? Ura : Uca;
  float* ssum     = s ? s_reg : s_cls;

  __shared__ __align__(16) short Kbuf[2][4][4][64][8];   // 32KB (double)
  __shared__ __align__(16) short Vbuf[2][8][2][64][8];   // 32KB (double)
  __shared__ __align__(16) short Ebuf[4][2][2][64][8];   // 16KB

  const int t8 = w * 8;   // this wave's first staging frag (8 per wave)

#define STAGE(DB, JN) do {                                                   \
    _Pragma("unroll")                                                        \
    for (int q8=0; q8<8; ++q8){                                              \
      int t = t8 + q8;                                                       \
      if (t < 16){                                                           \
        int jf = t >> 2, kk = t & 3;                                         \
        gld16(Kp + (hN + (JN) + jf*16 + fr)*128 + kk*32 + fk8,               \
              &Kbuf[DB][jf][kk][0][0]);                                      \
      } else {                                                               \
        int u = t - 16, df = u >> 1, ks = u & 1;                             \
        gld16(vT + (hD + df*16 + fr)*2048 + (JN) + ks*32 + fk8,              \
              &Vbuf[DB][df][ks][0][0]);                                      \
      }                                                                      \
    }                                                                        \
  } while(0)

  bf16x8 aq[2][4];
  #pragma unroll
  for (int i2=0;i2<2;i2++)
    #pragma unroll
    for (int kk=0;kk<4;kk++)
      aq[i2][kk] = *(const bf16x8*)&Qp[(hN + iw + i2*16 + fr)*128 + kk*32 + fk8];

  float sci[2][4];
  #pragma unroll
  for (int i2=0;i2<2;i2++)
    #pragma unroll
    for (int r=0;r<4;r++)
      sci[i2][r] = sc[iw + i2*16 + (l>>4)*4 + r];

  f32x4 U[2][8] = {};
  float p[2][4] = {};

  const int ebyte = l & 7;
  const int ehi   = (l >> 3) & 1;
  const int jbase = js * JLEN;

  STAGE(0, jbase);
  __syncthreads();

  #pragma unroll
  for (int jt = 0; jt < 8; ++jt){
    const int db = jt & 1;
    const int j0 = jbase + jt*64;
    if (jt < 7) STAGE(db^1, j0 + 64);      // issue next tile before compute
    // ---- QK + exp + E-relayout (from buf db) ----
    #pragma unroll
    for (int jf=0; jf<4; ++jf){
      f32x4 S0 = {}; f32x4 S1 = {};
      #pragma unroll
      for (int kk=0; kk<4; ++kk){
        bf16x8 b = *(const bf16x8*)&Kbuf[db][jf][kk][l][0];
        S0 = MFMA16(aq[0][kk], b, S0);
        S1 = MFMA16(aq[1][kk], b, S1);
      }
      float sj = sc[j0 + jf*16 + fr];
      float sj25 = 25.0f * sj;
      const int ks  = jf >> 1;
      const int sub = ((jf & 1) << 1) | ehi;
      #pragma unroll
      for (int r=0;r<4;r++){
        float e0 = (sj > sci[0][r]-0.1f) ? __expf(S0[r]*sj25) : 1.0f;
        float e1 = (sj > sci[1][r]-0.1f) ? __expf(S1[r]*sj25) : 1.0f;
        p[0][r] += e0; p[1][r] += e1;
        int lrow = (l>>4)*4 + r + (sub<<4);
        Ebuf[w][0][ks][lrow][ebyte] = f2bf(e0);
        Ebuf[w][1][ks][lrow][ebyte] = f2bf(e1);
      }
    }
    // ---- PV ----
    #pragma unroll
    for (int ks=0; ks<2; ++ks){
      bf16x8 ef0 = *(const bf16x8*)&Ebuf[w][0][ks][l][0];
      bf16x8 ef1 = *(const bf16x8*)&Ebuf[w][1][ks][l][0];
      #pragma unroll
      for (int df=0; df<8; ++df){
        bf16x8 bv = *(const bf16x8*)&Vbuf[db][df][ks][l][0];
        U[0][df] = MFMA16(ef0, bv, U[0][df]);
        U[1][df] = MFMA16(ef1, bv, U[1][df]);
      }
    }
    __syncthreads();   // drains this wave's STAGE loads + protects buffers
  }
#undef STAGE

  // ---- row sums (reduce over lane bits 0..3) + atomics ----
  #pragma unroll
  for (int m=1;m<16;m<<=1)
    #pragma unroll
    for (int i2=0;i2<2;i2++)
      #pragma unroll
      for (int r=0;r<4;r++) p[i2][r] += __shfl_xor(p[i2][r], m);
  if (fr == 0){
    #pragma unroll
    for (int i2=0;i2<2;i2++)
      #pragma unroll
      for (int r=0;r<4;r++)
        atomAddF(&ssum[hN + iw + i2*16 + (l>>4)*4 + r], p[i2][r]);
  }
  #pragma unroll
  for (int i2=0;i2<2;i2++)
    #pragma unroll
    for (int df=0;df<8;df++)
      #pragma unroll
      for (int r=0;r<4;r++)
        atomAddF(&Uacc[(hN + iw + i2*16 + (l>>4)*4 + r)*128 + df*16 + fr],
                 U[i2][df][r]);
}

// ---------------------------------------------------------------------------
// Kernel 4b: combine partials -> x half of out = 0.5*(Uc/sc + Ur/sr)
// ---------------------------------------------------------------------------
__global__ __launch_bounds__(256,8) void k_attn_fin(
    const float* __restrict__ Uca, const float* __restrict__ Ura,
    const float* __restrict__ s_cls, const float* __restrict__ s_reg,
    float* __restrict__ out)
{
  int task = blockIdx.x*4 + (threadIdx.x>>6);   // h*2048 + row
  int lane = threadIdx.x & 63;
  int h = task >> 11;
  int row = task & 2047;
  size_t b = (size_t)task*128 + lane*2;
  float2 uc = *(const float2*)(Uca + b);
  float2 ur = *(const float2*)(Ura + b);
  float isc = 0.5f/s_cls[task];
  float isr = 0.5f/s_reg[task];
  float2 o = { uc.x*isc + ur.x*isr, uc.y*isc + ur.y*isr };
  *(float2*)&out[(size_t)row*2048 + h*128 + lane*2] = o;
}

// ---------------------------------------------------------------------------
// Kernel 5: sim_attn. Block tile 128i x 64j, 4 waves; frag-major LDS staging.
// ---------------------------------------------------------------------------
__global__ __launch_bounds__(256,2) void k_sim(
    const short* __restrict__ qc, const short* __restrict__ kc,
    const short* __restrict__ qr, const short* __restrict__ kr,
    const float* __restrict__ csc, const float* __restrict__ fsc,
    const float* __restrict__ s_cls, const float* __restrict__ s_reg,
    float* __restrict__ out)
{
  const int tid  = threadIdx.x;
  const int lane = tid & 63;
  const int w    = tid >> 6;
  const int i0w  = blockIdx.x * 128 + w * 32;
  const int j0   = blockIdx.y * 64;
  const int fr   = lane & 15;
  const int fk   = (lane >> 4) * 8;

  __shared__ __align__(16) short Bsh[2][16][64][8];   // 32 KiB

  float sjc[4], sjf[4];
  #pragma unroll
  for (int js=0;js<4;js++){ sjc[js]=csc[j0+js*16+fr]; sjf[js]=fsc[j0+js*16+fr]; }
  int rowb[2]; float sci[2][4], sfi[2][4];
  #pragma unroll
  for (int ri=0;ri<2;ri++){
    rowb[ri] = i0w + ri*16 + ((lane>>4)<<2);
    #pragma unroll
    for (int r=0;r<4;r++){ sci[ri][r]=csc[rowb[ri]+r]; sfi[ri][r]=fsc[rowb[ri]+r]; }
  }

  f32x4 sim[2][4] = {};

  for (int h=0; h<8; ++h){
    const size_t hb = (size_t)h * NTOK;
    bf16x8 aq[2][4], ar[2][4];
    #pragma unroll
    for (int ri=0;ri<2;ri++)
      #pragma unroll
      for (int kk=0;kk<4;kk++){
        aq[ri][kk] = *(const bf16x8*)&qc[(hb + i0w + ri*16 + fr)*128 + kk*32 + fk];
        ar[ri][kk] = *(const bf16x8*)&qr[(hb + i0w + ri*16 + fr)*128 + kk*32 + fk];
      }
    float iscl[2][4], isrl[2][4];
    #pragma unroll
    for (int ri=0;ri<2;ri++)
      #pragma unroll
      for (int r=0;r<4;r++){
        iscl[ri][r] = 1.0f/s_cls[hb + rowb[ri] + r];
        isrl[ri][r] = 1.0f/s_reg[hb + rowb[ri] + r];
      }
    __syncthreads();
    #pragma unroll
    for (int it=0; it<8; ++it){
      int slot = it*256 + tid;
      int str  = slot >> 10;
      int frag = (slot >> 6) & 15;
      int l    = slot & 63;
      int r    = (frag >> 2)*16 + (l & 15);
      int c    = (frag & 3)*32 + (l >> 4)*8;
      const short* gp = (str ? kr : kc) + (hb + j0 + r)*128 + c;
      *(bf16x8*)&Bsh[str][frag][l][0] = *(const bf16x8*)gp;
    }
    __syncthreads();
    #pragma unroll
    for (int js=0; js<4; ++js){
      bf16x8 bc[4], br[4];
      #pragma unroll
      for (int kk=0;kk<4;kk++){
        bc[kk] = *(const bf16x8*)&Bsh[0][js*4+kk][lane][0];
        br[kk] = *(const bf16x8*)&Bsh[1][js*4+kk][lane][0];
      }
      #pragma unroll
      for (int ri=0;ri<2;ri++){
        f32x4 Sc = {}; f32x4 Sr = {};
        #pragma unroll
        for (int kk=0;kk<4;kk++){
          Sc = MFMA16(aq[ri][kk], bc[kk], Sc);
          Sr = MFMA16(ar[ri][kk], br[kk], Sr);
        }
        #pragma unroll
        for (int r=0;r<4;r++){
          float ec = (sjc[js] > sci[ri][r]-0.1f) ? __expf(Sc[r]*(25.0f*sjc[js])) : 1.0f;
          float er = (sjf[js] > sfi[ri][r]-0.1f) ? __expf(Sr[r]*(25.0f*sjf[js])) : 1.0f;
          sim[ri][js][r] += ec*iscl[ri][r] + er*isrl[ri][r];
        }
      }
    }
  }
  #pragma unroll
  for (int ri=0;ri<2;ri++)
    #pragma unroll
    for (int js=0;js<4;js++)
      #pragma unroll
      for (int r=0;r<4;r++)
        out[4194304ull + (size_t)(rowb[ri]+r)*2048 + j0 + js*16 + fr]
            = sim[ri][js][r] * 0.0625f;
}

// ---------------------------------------------------------------------------
// Kernel 5b: raw = Vn . Vn^T over full C=1024; mask = raw>6.
// ---------------------------------------------------------------------------
__global__ __launch_bounds__(256,4) void k_raw(
    const short* __restrict__ vn, unsigned char* __restrict__ mask)
{
  const int tid  = threadIdx.x;
  const int lane = tid & 63;
  const int w    = tid >> 6;
  const int i0w  = blockIdx.x * 128 + w * 32;
  const int j0   = blockIdx.y * 64;
  const int fr   = lane & 15;
  const int fk   = (lane >> 4) * 8;

  __shared__ __align__(16) short Bsh[16][64][8];   // 16 KiB

  f32x4 raw[2][4] = {};

  for (int cc=0; cc<8; ++cc){
    const size_t hb = (size_t)cc * NTOK;
    bf16x8 av[2][4];
    #pragma unroll
    for (int ri=0;ri<2;ri++)
      #pragma unroll
      for (int kk=0;kk<4;kk++)
        av[ri][kk] = *(const bf16x8*)&vn[(hb + i0w + ri*16 + fr)*128 + kk*32 + fk];
    __syncthreads();
    #pragma unroll
    for (int it=0; it<4; ++it){
      int slot = it*256 + tid;
      int frag = (slot >> 6) & 15;
      int l    = slot & 63;
      int r    = (frag >> 2)*16 + (l & 15);
      int c    = (frag & 3)*32 + (l >> 4)*8;
      *(bf16x8*)&Bsh[frag][l][0] = *(const bf16x8*)&vn[(hb + j0 + r)*128 + c];
    }
    __syncthreads();
    #pragma unroll
    for (int js=0; js<4; ++js){
      bf16x8 bv[4];
      #pragma unroll
      for (int kk=0;kk<4;kk++) bv[kk] = *(const bf16x8*)&Bsh[js*4+kk][lane][0];
      #pragma unroll
      for (int ri=0;ri<2;ri++)
        #pragma unroll
        for (int kk=0;kk<4;kk++)
          raw[ri][js] = MFMA16(av[ri][kk], bv[kk], raw[ri][js]);
    }
  }
  const int rb0 = i0w + ((lane>>4)<<2);
  #pragma unroll
  for (int ri=0;ri<2;ri++)
    #pragma unroll
    for (int js=0;js<4;js++)
      #pragma unroll
      for (int r=0;r<4;r++)
        mask[(size_t)(rb0 + ri*16 + r)*2048 + j0 + js*16 + fr]
            = raw[ri][js][r] > 6.0f ? 1 : 0;
}

// ---------------------------------------------------------------------------
// Kernel 6: final masked renorm (in place on sim half of out).
// ---------------------------------------------------------------------------
__global__ __launch_bounds__(256,4) void k_final(
    float* __restrict__ out, const unsigned char* __restrict__ mask)
{
  int row  = blockIdx.x*4 + (threadIdx.x>>6);
  int lane = threadIdx.x & 63;
  float* sr = out + 4194304ull + (size_t)row*2048;
  const unsigned char* mr = mask + (size_t)row*2048;
  float v[32];
  float sum2 = 0.0f;
  #pragma unroll
  for (int c=0;c<32;c++){
    float e = __expf(sr[c*64 + lane]);
    v[c] = (mr[c*64 + lane] != 0) ? e : 0.0f;
    sum2 += v[c];
  }
  #pragma unroll
  for (int m=1;m<64;m<<=1) sum2 += __shfl_xor(sum2, m);
  float inv = 1.0f / sum2;
  #pragma unroll
  for (int c=0;c<32;c++) sr[c*64 + lane] = v[c]*inv;
}

// ---------------------------------------------------------------------------
extern "C" void kernel_launch(void* const* d_in, const int* in_sizes, int n_in,
                              void* d_out, int out_size, void* d_ws, size_t ws_size,
                              hipStream_t stream)
{
  const float* xcls = (const float*)d_in[0];
  const float* xreg = (const float*)d_in[1];
  const float* csc  = (const float*)d_in[2];
  const float* fsc  = (const float*)d_in[3];
  const float* Wc   = (const float*)d_in[4];
  const float* Wr   = (const float*)d_in[5];
  float* out = (float*)d_out;

  char* ws = (char*)d_ws;
  // tmp f32 [0, 41.94MB) -- dead after k_norm; overlays:
  //   mask @0 (4MB); s_cls/s_reg @8MB (128KB); Uca/Ura @8MB+128K (16.8MB)
  float* tmp          = (float*)ws;
  unsigned char* mask = (unsigned char*)ws;
  char* accbase       = ws + 8u*1024*1024;
  float* s_cls        = (float*)(accbase);
  float* s_reg        = (float*)(accbase + 65536);
  float* Uca          = (float*)(accbase + 131072);
  float* Ura          = (float*)(accbase + 131072 + 8388608);
  size_t acc_bytes    = 131072 + 2*8388608;
  short* qc = (short*)(ws + 41943040ull);
  short* kc = qc + 2097152;
  short* qr = kc + 2097152;
  short* kr = qr + 2097152;
  short* vn = kr + 2097152;
  short* vb = vn + 2097152;
  short* vT = vb + 2097152;

  k_qkv  <<<dim3(32,80), 256, 0, stream>>>(xcls, xreg, Wc, Wr, tmp);
  k_norm <<<20480,       256, 0, stream>>>(tmp, out, qc, kc, qr, kr, vn, vb);
  k_vT   <<<512,         256, 0, stream>>>(vb, vT);
  hipMemsetAsync(accbase, 0, acc_bytes, stream);
  k_attn <<<1024,        256, 0, stream>>>(qc, kc, qr, kr, vT, csc, fsc,
                                           s_cls, s_reg, Uca, Ura);
  k_attn_fin <<<4096,    256, 0, stream>>>(Uca, Ura, s_cls, s_reg, out);
  k_raw  <<<dim3(16,32), 256, 0, stream>>>(vn, mask);
  k_sim  <<<dim3(16,32), 256, 0, stream>>>(qc, kc, qr, kr, csc, fsc, s_cls, s_reg, out);
  k_final<<<512,         256, 0, stream>>>(out, mask);
}

// Round 6
// 295.269 us; speedup vs baseline: 1.8173x; 1.3578x over previous
//
#include <hip/hip_runtime.h>

// ---------------------------------------------------------------------------
// Attention_msa: B=1, N=2048, C=1024, H=8, d=128, SCALE=25, SIM_THRESH=0.75
// ---------------------------------------------------------------------------

#define NTOK 2048
#define CDIM 1024
#define OD   5120   // 3C (cls: q,k,v) + 2C (reg: q,k)

typedef __attribute__((ext_vector_type(8))) short bf16x8;
typedef __attribute__((ext_vector_type(4))) short s16x4;
typedef __attribute__((ext_vector_type(2))) short s16x2;
typedef __attribute__((ext_vector_type(4))) float f32x4;

#define MFMA16(a,b,c) __builtin_amdgcn_mfma_f32_16x16x32_bf16((a),(b),(c),0,0,0)

__device__ __forceinline__ short f2bf(float x){
  unsigned u = __float_as_uint(x);
  u += 0x7FFFu + ((u >> 16) & 1u);           // round-to-nearest-even
  return (short)(u >> 16);
}

__device__ __forceinline__ void atomAddF(float* p, float v){
  unsafeAtomicAdd(p, v);                     // global_atomic_add_f32
}

// async global->LDS, 16B per lane; LDS dest = uniform base + lane*16
__device__ __forceinline__ void gld16(const short* g, short* l){
  __builtin_amdgcn_global_load_lds(
      (const __attribute__((address_space(1))) unsigned int*)g,
      (__attribute__((address_space(3))) unsigned int*)l, 16, 0, 0);
}

// ---------------------------------------------------------------------------
// Kernel 1: QKV GEMM.  tmp[m][o] = X[m][:] . W[o][:],  o in [0,5120)
// ---------------------------------------------------------------------------
__global__ __launch_bounds__(256,2) void k_qkv(
    const float* __restrict__ xcls, const float* __restrict__ xreg,
    const float* __restrict__ Wcls, const float* __restrict__ Wreg,
    float* __restrict__ tmp)
{
  const int m0 = blockIdx.x * 64;
  const int o0 = blockIdx.y * 64;
  const float* X; const float* W; int wrow;
  if (o0 < 3072){ X = xcls; W = Wcls; wrow = o0; }
  else          { X = xreg; W = Wreg; wrow = o0 - 3072; }

  __shared__ short As[64][40];
  __shared__ short Bs[64][40];

  const int tid  = threadIdx.x;
  const int lane = tid & 63;
  const int wid  = tid >> 6;
  const int wm   = (wid >> 1) * 32;
  const int wo   = (wid & 1) * 32;
  const int fr   = lane & 15;
  const int fk   = (lane >> 4) * 8;

  f32x4 acc[2][2] = {};

  for (int k0 = 0; k0 < CDIM; k0 += 32){
    #pragma unroll
    for (int it = 0; it < 2; ++it){
      int idx = tid + it*256;
      int r = idx >> 3;
      int c = (idx & 7) << 2;
      float4 xv = *(const float4*)(X + (size_t)(m0+r)*CDIM + k0 + c);
      *(s16x4*)&As[r][c] = (s16x4){ f2bf(xv.x), f2bf(xv.y), f2bf(xv.z), f2bf(xv.w) };
      float4 wv = *(const float4*)(W + (size_t)(wrow+r)*CDIM + k0 + c);
      *(s16x4*)&Bs[r][c] = (s16x4){ f2bf(wv.x), f2bf(wv.y), f2bf(wv.z), f2bf(wv.w) };
    }
    __syncthreads();
    bf16x8 a0 = *(const bf16x8*)&As[wm      + fr][fk];
    bf16x8 a1 = *(const bf16x8*)&As[wm + 16 + fr][fk];
    bf16x8 b0 = *(const bf16x8*)&Bs[wo      + fr][fk];
    bf16x8 b1 = *(const bf16x8*)&Bs[wo + 16 + fr][fk];
    acc[0][0] = MFMA16(a0,b0,acc[0][0]);
    acc[0][1] = MFMA16(a0,b1,acc[0][1]);
    acc[1][0] = MFMA16(a1,b0,acc[1][0]);
    acc[1][1] = MFMA16(a1,b1,acc[1][1]);
    __syncthreads();
  }
  #pragma unroll
  for (int fi=0;fi<2;fi++)
    #pragma unroll
    for (int fj=0;fj<2;fj++)
      #pragma unroll
      for (int r=0;r<4;r++){
        int mm = m0 + wm + fi*16 + (lane>>4)*4 + r;
        int oo = o0 + wo + fj*16 + fr;
        tmp[(size_t)mm*OD + oo] = acc[fi][fj][r];
      }
}

// ---------------------------------------------------------------------------
// Kernel 2: per-(n,chunk,head) L2 norm + scatter to bf16 buffers.
// ---------------------------------------------------------------------------
__global__ __launch_bounds__(256,4) void k_norm(
    const float* __restrict__ tmp, float* __restrict__ out,
    short* __restrict__ qc, short* __restrict__ kc,
    short* __restrict__ qr, short* __restrict__ kr,
    short* __restrict__ vn, short* __restrict__ vb)
{
  int task = blockIdx.x*4 + (threadIdx.x>>6);
  int lane = threadIdx.x & 63;
  int n = task / 40;
  int rem = task - n*40;
  int chunk = rem >> 3;
  int h = rem & 7;
  const float* src = tmp + (size_t)n*OD + (chunk<<10) + h*128;
  float2 v = *(const float2*)(src + lane*2);
  float ss = v.x*v.x + v.y*v.y;
  #pragma unroll
  for (int m=1;m<64;m<<=1) ss += __shfl_xor(ss, m);
  float rn = 1.0f / sqrtf(ss);
  size_t base = ((size_t)h*NTOK + n)*128 + lane*2;
  s16x2 nv = { f2bf(v.x*rn), f2bf(v.y*rn) };
  switch(chunk){
    case 0: *(s16x2*)&qc[base] = nv; break;
    case 1: *(s16x2*)&kc[base] = nv; break;
    case 3: *(s16x2*)&qr[base] = nv; break;
    case 4: *(s16x2*)&kr[base] = nv; break;
    default: {
      *(s16x2*)&vn[base] = nv;
      *(s16x2*)&vb[base] = (s16x2){ f2bf(v.x), f2bf(v.y) };
      *(float2*)&out[(size_t)n*2048 + 1024 + h*128 + lane*2] = v;
      break;
    }
  }
}

// ---------------------------------------------------------------------------
// Kernel 3: transpose raw v (bf16) [h][n][d] -> vT [h][d][n]
// ---------------------------------------------------------------------------
__global__ __launch_bounds__(256,4) void k_vT(
    const short* __restrict__ vb, short* __restrict__ vT)
{
  int b = blockIdx.x;
  int h  = b >> 6;
  int nt = (b >> 1) & 31;
  int dt = b & 1;
  __shared__ short t[64][72];
  int tid = threadIdx.x;
  int r  = tid >> 2;
  int c0 = (tid & 3) << 4;
  #pragma unroll
  for (int u=0;u<2;u++){
    bf16x8 val = *(const bf16x8*)&vb[((size_t)h*NTOK + nt*64 + r)*128 + dt*64 + c0 + u*8];
    #pragma unroll
    for (int e=0;e<8;e++) t[r][c0+u*8+e] = val[e];
  }
  __syncthreads();
  #pragma unroll
  for (int u=0;u<2;u++){
    bf16x8 o;
    #pragma unroll
    for (int e=0;e<8;e++) o[e] = t[c0+u*8+e][r];
    *(bf16x8*)&vT[((size_t)h*128 + dt*64 + r)*NTOK + nt*64 + c0 + u*8] = o;
  }
}

// ---------------------------------------------------------------------------
// Kernel 4: attention partial pass. NO U-atomics: JSPLIT=2, each block plain-
// stores its partial U into a (js,stream)-indexed buffer; fin sums 2 partials.
// Swizzle: both j-splits + all 16 i-blocks of one (h,s) on ONE XCD (2 (h,s)
// groups/XCD, K+V = 2MB < 4MB L2). Double-buffered global_load_lds staging.
// ---------------------------------------------------------------------------
#define JLEN 1024

__global__ __launch_bounds__(256,2) void k_attn(
    const short* __restrict__ qc, const short* __restrict__ kc,
    const short* __restrict__ qr, const short* __restrict__ kr,
    const short* __restrict__ vT,
    const float* __restrict__ csc, const float* __restrict__ fsc,
    float* __restrict__ s_cls, float* __restrict__ s_reg,
    float* __restrict__ Up)
{
  const int tid = threadIdx.x;
  const int l   = tid & 63;
  const int w   = tid >> 6;
  // XCD-grouped swizzle: block L lands on XCD L&7 (round-robin dispatch).
  const int L    = blockIdx.x;            // 0..511
  const int xcd  = L & 7;
  const int slot = L >> 3;                // 0..63
  const int hs   = ((slot >> 5) << 3) | xcd;   // 0..15 : 2 (h,s) groups/XCD
  const int h    = hs >> 1;
  const int s    = hs & 1;
  const int rem  = slot & 31;
  const int js   = rem >> 4;
  const int ib   = rem & 15;

  const int iw  = ib * 128 + w * 32;           // wave's first row
  const int fr  = l & 15;
  const int fk8 = (l >> 4) * 8;
  const size_t hN = (size_t)h * NTOK;
  const size_t hD = (size_t)h * 128;

  const short* Qp = s ? qr : qc;
  const short* Kp = s ? kr : kc;
  const float* sc = s ? fsc : csc;
  float* ssum     = s ? s_reg : s_cls;
  float* Ub       = Up + (size_t)(js*2 + s) * 2097152;   // partial buffer

  __shared__ __align__(16) short Kbuf[2][4][4][64][8];   // 32KB (double)
  __shared__ __align__(16) short Vbuf[2][8][2][64][8];   // 32KB (double)
  __shared__ __align__(16) short Ebuf[4][2][2][64][8];   // 16KB

  const int t8 = w * 8;   // this wave's first staging frag (8 per wave)

#define STAGE(DB, JN) do {                                                   \
    _Pragma("unroll")                                                        \
    for (int q8=0; q8<8; ++q8){                                              \
      int t = t8 + q8;                                                       \
      if (t < 16){                                                           \
        int jf = t >> 2, kk = t & 3;                                         \
        gld16(Kp + (hN + (JN) + jf*16 + fr)*128 + kk*32 + fk8,               \
              &Kbuf[DB][jf][kk][0][0]);                                      \
      } else {                                                               \
        int u = t - 16, df = u >> 1, ks = u & 1;                             \
        gld16(vT + (hD + df*16 + fr)*2048 + (JN) + ks*32 + fk8,              \
              &Vbuf[DB][df][ks][0][0]);                                      \
      }                                                                      \
    }                                                                        \
  } while(0)

  bf16x8 aq[2][4];
  #pragma unroll
  for (int i2=0;i2<2;i2++)
    #pragma unroll
    for (int kk=0;kk<4;kk++)
      aq[i2][kk] = *(const bf16x8*)&Qp[(hN + iw + i2*16 + fr)*128 + kk*32 + fk8];

  float sci[2][4];
  #pragma unroll
  for (int i2=0;i2<2;i2++)
    #pragma unroll
    for (int r=0;r<4;r++)
      sci[i2][r] = sc[iw + i2*16 + (l>>4)*4 + r];

  f32x4 U[2][8] = {};
  float p[2][4] = {};

  const int ebyte = l & 7;
  const int ehi   = (l >> 3) & 1;
  const int jbase = js * JLEN;

  STAGE(0, jbase);
  __syncthreads();

  for (int jt = 0; jt < 16; ++jt){
    const int db = jt & 1;
    const int j0 = jbase + jt*64;
    if (jt < 15){ if (db) STAGE(0, j0 + 64); else STAGE(1, j0 + 64); }
    // ---- QK + exp + E-relayout (from buf db) ----
    #pragma unroll
    for (int jf=0; jf<4; ++jf){
      f32x4 S0 = {}; f32x4 S1 = {};
      #pragma unroll
      for (int kk=0; kk<4; ++kk){
        bf16x8 b = *(const bf16x8*)&Kbuf[db][jf][kk][l][0];
        S0 = MFMA16(aq[0][kk], b, S0);
        S1 = MFMA16(aq[1][kk], b, S1);
      }
      float sj = sc[j0 + jf*16 + fr];
      float sj25 = 25.0f * sj;
      const int ks  = jf >> 1;
      const int sub = ((jf & 1) << 1) | ehi;
      #pragma unroll
      for (int r=0;r<4;r++){
        float e0 = (sj > sci[0][r]-0.1f) ? __expf(S0[r]*sj25) : 1.0f;
        float e1 = (sj > sci[1][r]-0.1f) ? __expf(S1[r]*sj25) : 1.0f;
        p[0][r] += e0; p[1][r] += e1;
        int lrow = (l>>4)*4 + r + (sub<<4);
        Ebuf[w][0][ks][lrow][ebyte] = f2bf(e0);
        Ebuf[w][1][ks][lrow][ebyte] = f2bf(e1);
      }
    }
    // ---- PV ----
    #pragma unroll
    for (int ks=0; ks<2; ++ks){
      bf16x8 ef0 = *(const bf16x8*)&Ebuf[w][0][ks][l][0];
      bf16x8 ef1 = *(const bf16x8*)&Ebuf[w][1][ks][l][0];
      #pragma unroll
      for (int df=0; df<8; ++df){
        bf16x8 bv = *(const bf16x8*)&Vbuf[db][df][ks][l][0];
        U[0][df] = MFMA16(ef0, bv, U[0][df]);
        U[1][df] = MFMA16(ef1, bv, U[1][df]);
      }
    }
    __syncthreads();   // drains this wave's STAGE loads + protects buffers
  }
#undef STAGE

  // ---- row sums (reduce over lane bits 0..3) + XCD-local atomics ----
  #pragma unroll
  for (int m=1;m<16;m<<=1)
    #pragma unroll
    for (int i2=0;i2<2;i2++)
      #pragma unroll
      for (int r=0;r<4;r++) p[i2][r] += __shfl_xor(p[i2][r], m);
  if (fr == 0){
    #pragma unroll
    for (int i2=0;i2<2;i2++)
      #pragma unroll
      for (int r=0;r<4;r++)
        atomAddF(&ssum[hN + iw + i2*16 + (l>>4)*4 + r], p[i2][r]);
  }
  // ---- partial U: plain coalesced stores, no RMW ----
  #pragma unroll
  for (int i2=0;i2<2;i2++)
    #pragma unroll
    for (int df=0;df<8;df++)
      #pragma unroll
      for (int r=0;r<4;r++)
        Ub[(hN + iw + i2*16 + (l>>4)*4 + r)*128 + df*16 + fr] = U[i2][df][r];
}

// ---------------------------------------------------------------------------
// Kernel 4b: combine partials -> x half of out = 0.5*(sum Uc/sc + sum Ur/sr)
// ---------------------------------------------------------------------------
__global__ __launch_bounds__(256,8) void k_attn_fin(
    const float* __restrict__ Up,
    const float* __restrict__ s_cls, const float* __restrict__ s_reg,
    float* __restrict__ out)
{
  int task = blockIdx.x*4 + (threadIdx.x>>6);   // h*2048 + row
  int lane = threadIdx.x & 63;
  int h = task >> 11;
  int row = task & 2047;
  size_t b = (size_t)task*128 + lane*2;
  float2 c0 = *(const float2*)(Up + 0*2097152 + b);   // js0, cls
  float2 r0 = *(const float2*)(Up + 1*2097152 + b);   // js0, reg
  float2 c1 = *(const float2*)(Up + 2*2097152 + b);   // js1, cls
  float2 r1 = *(const float2*)(Up + 3*2097152 + b);   // js1, reg
  float isc = 0.5f/s_cls[task];
  float isr = 0.5f/s_reg[task];
  float2 o = { (c0.x+c1.x)*isc + (r0.x+r1.x)*isr,
               (c0.y+c1.y)*isc + (r0.y+r1.y)*isr };
  *(float2*)&out[(size_t)row*2048 + h*128 + lane*2] = o;
}

// ---------------------------------------------------------------------------
// Kernel 5: sim_attn. Block tile 128i x 64j, 4 waves; frag-major LDS staging.
// ---------------------------------------------------------------------------
__global__ __launch_bounds__(256,2) void k_sim(
    const short* __restrict__ qc, const short* __restrict__ kc,
    const short* __restrict__ qr, const short* __restrict__ kr,
    const float* __restrict__ csc, const float* __restrict__ fsc,
    const float* __restrict__ s_cls, const float* __restrict__ s_reg,
    float* __restrict__ out)
{
  const int tid  = threadIdx.x;
  const int lane = tid & 63;
  const int w    = tid >> 6;
  const int i0w  = blockIdx.x * 128 + w * 32;
  const int j0   = blockIdx.y * 64;
  const int fr   = lane & 15;
  const int fk   = (lane >> 4) * 8;

  __shared__ __align__(16) short Bsh[2][16][64][8];   // 32 KiB

  float sjc[4], sjf[4];
  #pragma unroll
  for (int js=0;js<4;js++){ sjc[js]=csc[j0+js*16+fr]; sjf[js]=fsc[j0+js*16+fr]; }
  int rowb[2]; float sci[2][4], sfi[2][4];
  #pragma unroll
  for (int ri=0;ri<2;ri++){
    rowb[ri] = i0w + ri*16 + ((lane>>4)<<2);
    #pragma unroll
    for (int r=0;r<4;r++){ sci[ri][r]=csc[rowb[ri]+r]; sfi[ri][r]=fsc[rowb[ri]+r]; }
  }

  f32x4 sim[2][4] = {};

  for (int h=0; h<8; ++h){
    const size_t hb = (size_t)h * NTOK;
    bf16x8 aq[2][4], ar[2][4];
    #pragma unroll
    for (int ri=0;ri<2;ri++)
      #pragma unroll
      for (int kk=0;kk<4;kk++){
        aq[ri][kk] = *(const bf16x8*)&qc[(hb + i0w + ri*16 + fr)*128 + kk*32 + fk];
        ar[ri][kk] = *(const bf16x8*)&qr[(hb + i0w + ri*16 + fr)*128 + kk*32 + fk];
      }
    float iscl[2][4], isrl[2][4];
    #pragma unroll
    for (int ri=0;ri<2;ri++)
      #pragma unroll
      for (int r=0;r<4;r++){
        iscl[ri][r] = 1.0f/s_cls[hb + rowb[ri] + r];
        isrl[ri][r] = 1.0f/s_reg[hb + rowb[ri] + r];
      }
    __syncthreads();
    #pragma unroll
    for (int it=0; it<8; ++it){
      int slot = it*256 + tid;
      int str  = slot >> 10;
      int frag = (slot >> 6) & 15;
      int l    = slot & 63;
      int r    = (frag >> 2)*16 + (l & 15);
      int c    = (frag & 3)*32 + (l >> 4)*8;
      const short* gp = (str ? kr : kc) + (hb + j0 + r)*128 + c;
      *(bf16x8*)&Bsh[str][frag][l][0] = *(const bf16x8*)gp;
    }
    __syncthreads();
    #pragma unroll
    for (int js=0; js<4; ++js){
      bf16x8 bc[4], br[4];
      #pragma unroll
      for (int kk=0;kk<4;kk++){
        bc[kk] = *(const bf16x8*)&Bsh[0][js*4+kk][lane][0];
        br[kk] = *(const bf16x8*)&Bsh[1][js*4+kk][lane][0];
      }
      #pragma unroll
      for (int ri=0;ri<2;ri++){
        f32x4 Sc = {}; f32x4 Sr = {};
        #pragma unroll
        for (int kk=0;kk<4;kk++){
          Sc = MFMA16(aq[ri][kk], bc[kk], Sc);
          Sr = MFMA16(ar[ri][kk], br[kk], Sr);
        }
        #pragma unroll
        for (int r=0;r<4;r++){
          float ec = (sjc[js] > sci[ri][r]-0.1f) ? __expf(Sc[r]*(25.0f*sjc[js])) : 1.0f;
          float er = (sjf[js] > sfi[ri][r]-0.1f) ? __expf(Sr[r]*(25.0f*sjf[js])) : 1.0f;
          sim[ri][js][r] += ec*iscl[ri][r] + er*isrl[ri][r];
        }
      }
    }
  }
  #pragma unroll
  for (int ri=0;ri<2;ri++)
    #pragma unroll
    for (int js=0;js<4;js++)
      #pragma unroll
      for (int r=0;r<4;r++)
        out[4194304ull + (size_t)(rowb[ri]+r)*2048 + j0 + js*16 + fr]
            = sim[ri][js][r] * 0.0625f;
}

// ---------------------------------------------------------------------------
// Kernel 5b: raw = Vn . Vn^T over full C=1024; mask = raw>6.
// ---------------------------------------------------------------------------
__global__ __launch_bounds__(256,4) void k_raw(
    const short* __restrict__ vn, unsigned char* __restrict__ mask)
{
  const int tid  = threadIdx.x;
  const int lane = tid & 63;
  const int w    = tid >> 6;
  const int i0w  = blockIdx.x * 128 + w * 32;
  const int j0   = blockIdx.y * 64;
  const int fr   = lane & 15;
  const int fk   = (lane >> 4) * 8;

  __shared__ __align__(16) short Bsh[16][64][8];   // 16 KiB

  f32x4 raw[2][4] = {};

  for (int cc=0; cc<8; ++cc){
    const size_t hb = (size_t)cc * NTOK;
    bf16x8 av[2][4];
    #pragma unroll
    for (int ri=0;ri<2;ri++)
      #pragma unroll
      for (int kk=0;kk<4;kk++)
        av[ri][kk] = *(const bf16x8*)&vn[(hb + i0w + ri*16 + fr)*128 + kk*32 + fk];
    __syncthreads();
    #pragma unroll
    for (int it=0; it<4; ++it){
      int slot = it*256 + tid;
      int frag = (slot >> 6) & 15;
      int l    = slot & 63;
      int r    = (frag >> 2)*16 + (l & 15);
      int c    = (frag & 3)*32 + (l >> 4)*8;
      *(bf16x8*)&Bsh[frag][l][0] = *(const bf16x8*)&vn[(hb + j0 + r)*128 + c];
    }
    __syncthreads();
    #pragma unroll
    for (int js=0; js<4; ++js){
      bf16x8 bv[4];
      #pragma unroll
      for (int kk=0;kk<4;kk++) bv[kk] = *(const bf16x8*)&Bsh[js*4+kk][lane][0];
      #pragma unroll
      for (int ri=0;ri<2;ri++)
        #pragma unroll
        for (int kk=0;kk<4;kk++)
          raw[ri][js] = MFMA16(av[ri][kk], bv[kk], raw[ri][js]);
    }
  }
  const int rb0 = i0w + ((lane>>4)<<2);
  #pragma unroll
  for (int ri=0;ri<2;ri++)
    #pragma unroll
    for (int js=0;js<4;js++)
      #pragma unroll
      for (int r=0;r<4;r++)
        mask[(size_t)(rb0 + ri*16 + r)*2048 + j0 + js*16 + fr]
            = raw[ri][js][r] > 6.0f ? 1 : 0;
}

// ---------------------------------------------------------------------------
// Kernel 6: final masked renorm (in place on sim half of out).
// ---------------------------------------------------------------------------
__global__ __launch_bounds__(256,4) void k_final(
    float* __restrict__ out, const unsigned char* __restrict__ mask)
{
  int row  = blockIdx.x*4 + (threadIdx.x>>6);
  int lane = threadIdx.x & 63;
  float* sr = out + 4194304ull + (size_t)row*2048;
  const unsigned char* mr = mask + (size_t)row*2048;
  float v[32];
  float sum2 = 0.0f;
  #pragma unroll
  for (int c=0;c<32;c++){
    float e = __expf(sr[c*64 + lane]);
    v[c] = (mr[c*64 + lane] != 0) ? e : 0.0f;
    sum2 += v[c];
  }
  #pragma unroll
  for (int m=1;m<64;m<<=1) sum2 += __shfl_xor(sum2, m);
  float inv = 1.0f / sum2;
  #pragma unroll
  for (int c=0;c<32;c++) sr[c*64 + lane] = v[c]*inv;
}

// ---------------------------------------------------------------------------
extern "C" void kernel_launch(void* const* d_in, const int* in_sizes, int n_in,
                              void* d_out, int out_size, void* d_ws, size_t ws_size,
                              hipStream_t stream)
{
  const float* xcls = (const float*)d_in[0];
  const float* xreg = (const float*)d_in[1];
  const float* csc  = (const float*)d_in[2];
  const float* fsc  = (const float*)d_in[3];
  const float* Wc   = (const float*)d_in[4];
  const float* Wr   = (const float*)d_in[5];
  float* out = (float*)d_out;

  char* ws = (char*)d_ws;
  // tmp f32 [0, 41.94MB) -- dead after k_norm; overlays:
  //   mask @0 (4MB); s_cls/s_reg @4MB (128KB); Up @4MB+128K (33.55MB -> 37.9MB)
  float* tmp          = (float*)ws;
  unsigned char* mask = (unsigned char*)ws;
  char* accbase       = ws + 4u*1024*1024;
  float* s_cls        = (float*)(accbase);
  float* s_reg        = (float*)(accbase + 65536);
  float* Up           = (float*)(accbase + 131072);   // 4 x 8.39MB partials
  short* qc = (short*)(ws + 41943040ull);
  short* kc = qc + 2097152;
  short* qr = kc + 2097152;
  short* kr = qr + 2097152;
  short* vn = kr + 2097152;
  short* vb = vn + 2097152;
  short* vT = vb + 2097152;

  k_qkv  <<<dim3(32,80), 256, 0, stream>>>(xcls, xreg, Wc, Wr, tmp);
  k_norm <<<20480,       256, 0, stream>>>(tmp, out, qc, kc, qr, kr, vn, vb);
  k_vT   <<<512,         256, 0, stream>>>(vb, vT);
  hipMemsetAsync(accbase, 0, 131072, stream);   // zero s_cls/s_reg only
  k_attn <<<512,         256, 0, stream>>>(qc, kc, qr, kr, vT, csc, fsc,
                                           s_cls, s_reg, Up);
  k_attn_fin <<<4096,    256, 0, stream>>>(Up, s_cls, s_reg, out);
  k_raw  <<<dim3(16,32), 256, 0, stream>>>(vn, mask);
  k_sim  <<<dim3(16,32), 256, 0, stream>>>(qc, kc, qr, kr, csc, fsc, s_cls, s_reg, out);
  k_final<<<512,         256, 0, stream>>>(out, mask);
}

// Round 7
// 254.818 us; speedup vs baseline: 2.1057x; 1.1587x over previous
//
#include <hip/hip_runtime.h>

// ---------------------------------------------------------------------------
// Attention_msa: B=1, N=2048, C=1024, H=8, d=128, SCALE=25, SIM_THRESH=0.75
// ---------------------------------------------------------------------------

#define NTOK 2048
#define CDIM 1024
#define OD   5120   // 3C (cls: q,k,v) + 2C (reg: q,k)

typedef __attribute__((ext_vector_type(8))) short bf16x8;
typedef __attribute__((ext_vector_type(4))) short s16x4;
typedef __attribute__((ext_vector_type(2))) short s16x2;
typedef __attribute__((ext_vector_type(4))) float f32x4;

#define MFMA16(a,b,c) __builtin_amdgcn_mfma_f32_16x16x32_bf16((a),(b),(c),0,0,0)

__device__ __forceinline__ short f2bf(float x){
  unsigned u = __float_as_uint(x);
  u += 0x7FFFu + ((u >> 16) & 1u);           // round-to-nearest-even
  return (short)(u >> 16);
}

__device__ __forceinline__ void atomAddF(float* p, float v){
  unsafeAtomicAdd(p, v);                     // global_atomic_add_f32
}

// async global->LDS, 16B per lane; LDS dest = uniform base + lane*16
__device__ __forceinline__ void gld16(const short* g, short* l){
  __builtin_amdgcn_global_load_lds(
      (const __attribute__((address_space(1))) unsigned int*)g,
      (__attribute__((address_space(3))) unsigned int*)l, 16, 0, 0);
}

// ---------------------------------------------------------------------------
// Kernel 0: f32 -> bf16 conversion of GEMM inputs (one pass).
// Chunks of 8 floats. Layout: [0,256K) xbc | [256K,512K) xbr |
// [512K,896K) wbc (3072 rows) | [896K,1152K) wbr (2048 rows).
// ---------------------------------------------------------------------------
__global__ __launch_bounds__(256,8) void k_cvt(
    const float* __restrict__ xc, const float* __restrict__ xr,
    const float* __restrict__ Wc, const float* __restrict__ Wr,
    short* __restrict__ xbc, short* __restrict__ xbr,
    short* __restrict__ wbc, short* __restrict__ wbr)
{
  int idx = blockIdx.x*256 + threadIdx.x;    // 0..1179647
  const float* src; short* dst; int off;
  if      (idx <  262144){ src = xc; dst = xbc; off = idx; }
  else if (idx <  524288){ src = xr; dst = xbr; off = idx - 262144; }
  else if (idx <  917504){ src = Wc; dst = wbc; off = idx - 524288; }
  else                   { src = Wr; dst = wbr; off = idx - 917504; }
  float4 a = *(const float4*)(src + (size_t)off*8);
  float4 b = *(const float4*)(src + (size_t)off*8 + 4);
  bf16x8 o = { f2bf(a.x), f2bf(a.y), f2bf(a.z), f2bf(a.w),
               f2bf(b.x), f2bf(b.y), f2bf(b.z), f2bf(b.w) };
  *(bf16x8*)(dst + (size_t)off*8) = o;
}

// ---------------------------------------------------------------------------
// Kernel 1: QKV GEMM (bf16 inputs).  tmp[m][o] = X[m][:] . W[o][:]
// 128x128 tile, BK=32, 4 waves (2x2, each 64x64 = 4x4 fragments).
// Frag-major LDS via global_load_lds with pre-swizzled global sources;
// double-buffered; XCD-grouped swizzle (5 W-panels x 16 m-blocks per XCD).
// ---------------------------------------------------------------------------
__global__ __launch_bounds__(256,3) void k_qkv(
    const short* __restrict__ xbc, const short* __restrict__ xbr,
    const short* __restrict__ wbc, const short* __restrict__ wbr,
    float* __restrict__ tmp)
{
  const int tid = threadIdx.x;
  const int l   = tid & 63;
  const int w   = tid >> 6;
  const int fr  = l & 15;
  const int fk8 = (l >> 4) * 8;

  // swizzle: 640 blocks; XCD (L&7) owns panels xcd*5..xcd*5+4, 16 m-blocks ea.
  const int L     = blockIdx.x;
  const int xcd   = L & 7;
  const int slot  = L >> 3;              // 0..79
  const int panel = xcd*5 + (slot >> 4); // 0..39
  const int mb    = slot & 15;
  const int m0    = mb * 128;
  const int o0    = panel * 128;

  const short* Xb; const short* Wb; int wrow;
  if (o0 < 3072){ Xb = xbc; Wb = wbc; wrow = o0; }
  else          { Xb = xbr; Wb = wbr; wrow = o0 - 3072; }

  __shared__ __align__(16) short Ab[2][8][64][8];   // 16KB (double)
  __shared__ __align__(16) short Bb[2][8][64][8];   // 16KB (double)

  const int wr = w >> 1;
  const int wc = w & 1;

#define QSTAGE(DB, KN) do {                                                  \
    _Pragma("unroll")                                                        \
    for (int it=0; it<2; ++it){                                              \
      int f = it*4 + w;                                                      \
      gld16(Xb + (size_t)(m0  + f*16 + fr)*CDIM + (KN) + fk8,                \
            &Ab[DB][f][0][0]);                                               \
      gld16(Wb + (size_t)(wrow + f*16 + fr)*CDIM + (KN) + fk8,               \
            &Bb[DB][f][0][0]);                                               \
    }                                                                        \
  } while(0)

  f32x4 acc[4][4] = {};

  QSTAGE(0, 0);
  __syncthreads();

  for (int kt = 0; kt < 32; ++kt){
    const int db = kt & 1;
    if (kt < 31){ if (db) QSTAGE(0, (kt+1)*32); else QSTAGE(1, (kt+1)*32); }
    bf16x8 af[4], bfr[4];
    #pragma unroll
    for (int ai=0;ai<4;ai++) af[ai]  = *(const bf16x8*)&Ab[db][wr*4+ai][l][0];
    #pragma unroll
    for (int bj=0;bj<4;bj++) bfr[bj] = *(const bf16x8*)&Bb[db][wc*4+bj][l][0];
    #pragma unroll
    for (int ai=0;ai<4;ai++)
      #pragma unroll
      for (int bj=0;bj<4;bj++)
        acc[ai][bj] = MFMA16(af[ai], bfr[bj], acc[ai][bj]);
    __syncthreads();
  }
#undef QSTAGE

  #pragma unroll
  for (int ai=0;ai<4;ai++)
    #pragma unroll
    for (int bj=0;bj<4;bj++)
      #pragma unroll
      for (int r=0;r<4;r++)
        tmp[(size_t)(m0 + wr*64 + ai*16 + (l>>4)*4 + r)*OD
            + o0 + wc*64 + bj*16 + fr] = acc[ai][bj][r];
}

// ---------------------------------------------------------------------------
// Kernel 2: per-(n,chunk,head) L2 norm + scatter to bf16 buffers.
// ---------------------------------------------------------------------------
__global__ __launch_bounds__(256,4) void k_norm(
    const float* __restrict__ tmp, float* __restrict__ out,
    short* __restrict__ qc, short* __restrict__ kc,
    short* __restrict__ qr, short* __restrict__ kr,
    short* __restrict__ vn, short* __restrict__ vb)
{
  int task = blockIdx.x*4 + (threadIdx.x>>6);
  int lane = threadIdx.x & 63;
  int n = task / 40;
  int rem = task - n*40;
  int chunk = rem >> 3;
  int h = rem & 7;
  const float* src = tmp + (size_t)n*OD + (chunk<<10) + h*128;
  float2 v = *(const float2*)(src + lane*2);
  float ss = v.x*v.x + v.y*v.y;
  #pragma unroll
  for (int m=1;m<64;m<<=1) ss += __shfl_xor(ss, m);
  float rn = 1.0f / sqrtf(ss);
  size_t base = ((size_t)h*NTOK + n)*128 + lane*2;
  s16x2 nv = { f2bf(v.x*rn), f2bf(v.y*rn) };
  switch(chunk){
    case 0: *(s16x2*)&qc[base] = nv; break;
    case 1: *(s16x2*)&kc[base] = nv; break;
    case 3: *(s16x2*)&qr[base] = nv; break;
    case 4: *(s16x2*)&kr[base] = nv; break;
    default: {
      *(s16x2*)&vn[base] = nv;
      *(s16x2*)&vb[base] = (s16x2){ f2bf(v.x), f2bf(v.y) };
      *(float2*)&out[(size_t)n*2048 + 1024 + h*128 + lane*2] = v;
      break;
    }
  }
}

// ---------------------------------------------------------------------------
// Kernel 3: transpose raw v (bf16) [h][n][d] -> vT [h][d][n]
// ---------------------------------------------------------------------------
__global__ __launch_bounds__(256,4) void k_vT(
    const short* __restrict__ vb, short* __restrict__ vT)
{
  int b = blockIdx.x;
  int h  = b >> 6;
  int nt = (b >> 1) & 31;
  int dt = b & 1;
  __shared__ short t[64][72];
  int tid = threadIdx.x;
  int r  = tid >> 2;
  int c0 = (tid & 3) << 4;
  #pragma unroll
  for (int u=0;u<2;u++){
    bf16x8 val = *(const bf16x8*)&vb[((size_t)h*NTOK + nt*64 + r)*128 + dt*64 + c0 + u*8];
    #pragma unroll
    for (int e=0;e<8;e++) t[r][c0+u*8+e] = val[e];
  }
  __syncthreads();
  #pragma unroll
  for (int u=0;u<2;u++){
    bf16x8 o;
    #pragma unroll
    for (int e=0;e<8;e++) o[e] = t[c0+u*8+e][r];
    *(bf16x8*)&vT[((size_t)h*128 + dt*64 + r)*NTOK + nt*64 + c0 + u*8] = o;
  }
}

// ---------------------------------------------------------------------------
// Kernel 4: attention partial pass (unchanged from R5).
// ---------------------------------------------------------------------------
#define JLEN 1024

__global__ __launch_bounds__(256,2) void k_attn(
    const short* __restrict__ qc, const short* __restrict__ kc,
    const short* __restrict__ qr, const short* __restrict__ kr,
    const short* __restrict__ vT,
    const float* __restrict__ csc, const float* __restrict__ fsc,
    float* __restrict__ s_cls, float* __restrict__ s_reg,
    float* __restrict__ Up)
{
  const int tid = threadIdx.x;
  const int l   = tid & 63;
  const int w   = tid >> 6;
  const int L    = blockIdx.x;            // 0..511
  const int xcd  = L & 7;
  const int slot = L >> 3;                // 0..63
  const int hs   = ((slot >> 5) << 3) | xcd;   // 0..15
  const int h    = hs >> 1;
  const int s    = hs & 1;
  const int rem  = slot & 31;
  const int js   = rem >> 4;
  const int ib   = rem & 15;

  const int iw  = ib * 128 + w * 32;
  const int fr  = l & 15;
  const int fk8 = (l >> 4) * 8;
  const size_t hN = (size_t)h * NTOK;
  const size_t hD = (size_t)h * 128;

  const short* Qp = s ? qr : qc;
  const short* Kp = s ? kr : kc;
  const float* sc = s ? fsc : csc;
  float* ssum     = s ? s_reg : s_cls;
  float* Ub       = Up + (size_t)(js*2 + s) * 2097152;

  __shared__ __align__(16) short Kbuf[2][4][4][64][8];
  __shared__ __align__(16) short Vbuf[2][8][2][64][8];
  __shared__ __align__(16) short Ebuf[4][2][2][64][8];

  const int t8 = w * 8;

#define STAGE(DB, JN) do {                                                   \
    _Pragma("unroll")                                                        \
    for (int q8=0; q8<8; ++q8){                                              \
      int t = t8 + q8;                                                       \
      if (t < 16){                                                           \
        int jf = t >> 2, kk = t & 3;                                         \
        gld16(Kp + (hN + (JN) + jf*16 + fr)*128 + kk*32 + fk8,               \
              &Kbuf[DB][jf][kk][0][0]);                                      \
      } else {                                                               \
        int u = t - 16, df = u >> 1, ks = u & 1;                             \
        gld16(vT + (hD + df*16 + fr)*2048 + (JN) + ks*32 + fk8,              \
              &Vbuf[DB][df][ks][0][0]);                                      \
      }                                                                      \
    }                                                                        \
  } while(0)

  bf16x8 aq[2][4];
  #pragma unroll
  for (int i2=0;i2<2;i2++)
    #pragma unroll
    for (int kk=0;kk<4;kk++)
      aq[i2][kk] = *(const bf16x8*)&Qp[(hN + iw + i2*16 + fr)*128 + kk*32 + fk8];

  float sci[2][4];
  #pragma unroll
  for (int i2=0;i2<2;i2++)
    #pragma unroll
    for (int r=0;r<4;r++)
      sci[i2][r] = sc[iw + i2*16 + (l>>4)*4 + r];

  f32x4 U[2][8] = {};
  float p[2][4] = {};

  const int ebyte = l & 7;
  const int ehi   = (l >> 3) & 1;
  const int jbase = js * JLEN;

  STAGE(0, jbase);
  __syncthreads();

  for (int jt = 0; jt < 16; ++jt){
    const int db = jt & 1;
    const int j0 = jbase + jt*64;
    if (jt < 15){ if (db) STAGE(0, j0 + 64); else STAGE(1, j0 + 64); }
    #pragma unroll
    for (int jf=0; jf<4; ++jf){
      f32x4 S0 = {}; f32x4 S1 = {};
      #pragma unroll
      for (int kk=0; kk<4; ++kk){
        bf16x8 b = *(const bf16x8*)&Kbuf[db][jf][kk][l][0];
        S0 = MFMA16(aq[0][kk], b, S0);
        S1 = MFMA16(aq[1][kk], b, S1);
      }
      float sj = sc[j0 + jf*16 + fr];
      float sj25 = 25.0f * sj;
      const int ks  = jf >> 1;
      const int sub = ((jf & 1) << 1) | ehi;
      #pragma unroll
      for (int r=0;r<4;r++){
        float e0 = (sj > sci[0][r]-0.1f) ? __expf(S0[r]*sj25) : 1.0f;
        float e1 = (sj > sci[1][r]-0.1f) ? __expf(S1[r]*sj25) : 1.0f;
        p[0][r] += e0; p[1][r] += e1;
        int lrow = (l>>4)*4 + r + (sub<<4);
        Ebuf[w][0][ks][lrow][ebyte] = f2bf(e0);
        Ebuf[w][1][ks][lrow][ebyte] = f2bf(e1);
      }
    }
    #pragma unroll
    for (int ks=0; ks<2; ++ks){
      bf16x8 ef0 = *(const bf16x8*)&Ebuf[w][0][ks][l][0];
      bf16x8 ef1 = *(const bf16x8*)&Ebuf[w][1][ks][l][0];
      #pragma unroll
      for (int df=0; df<8; ++df){
        bf16x8 bv = *(const bf16x8*)&Vbuf[db][df][ks][l][0];
        U[0][df] = MFMA16(ef0, bv, U[0][df]);
        U[1][df] = MFMA16(ef1, bv, U[1][df]);
      }
    }
    __syncthreads();
  }
#undef STAGE

  #pragma unroll
  for (int m=1;m<16;m<<=1)
    #pragma unroll
    for (int i2=0;i2<2;i2++)
      #pragma unroll
      for (int r=0;r<4;r++) p[i2][r] += __shfl_xor(p[i2][r], m);
  if (fr == 0){
    #pragma unroll
    for (int i2=0;i2<2;i2++)
      #pragma unroll
      for (int r=0;r<4;r++)
        atomAddF(&ssum[hN + iw + i2*16 + (l>>4)*4 + r], p[i2][r]);
  }
  #pragma unroll
  for (int i2=0;i2<2;i2++)
    #pragma unroll
    for (int df=0;df<8;df++)
      #pragma unroll
      for (int r=0;r<4;r++)
        Ub[(hN + iw + i2*16 + (l>>4)*4 + r)*128 + df*16 + fr] = U[i2][df][r];
}

// ---------------------------------------------------------------------------
// Kernel 4b: combine partials -> x half of out = 0.5*(sum Uc/sc + sum Ur/sr)
// ---------------------------------------------------------------------------
__global__ __launch_bounds__(256,8) void k_attn_fin(
    const float* __restrict__ Up,
    const float* __restrict__ s_cls, const float* __restrict__ s_reg,
    float* __restrict__ out)
{
  int task = blockIdx.x*4 + (threadIdx.x>>6);   // h*2048 + row
  int lane = threadIdx.x & 63;
  int h = task >> 11;
  int row = task & 2047;
  size_t b = (size_t)task*128 + lane*2;
  float2 c0 = *(const float2*)(Up + 0*2097152 + b);
  float2 r0 = *(const float2*)(Up + 1*2097152 + b);
  float2 c1 = *(const float2*)(Up + 2*2097152 + b);
  float2 r1 = *(const float2*)(Up + 3*2097152 + b);
  float isc = 0.5f/s_cls[task];
  float isr = 0.5f/s_reg[task];
  float2 o = { (c0.x+c1.x)*isc + (r0.x+r1.x)*isr,
               (c0.y+c1.y)*isc + (r0.y+r1.y)*isr };
  *(float2*)&out[(size_t)row*2048 + h*128 + lane*2] = o;
}

// ---------------------------------------------------------------------------
// Kernel 5: sim_attn. Block tile 128i x 64j, 4 waves; frag-major LDS staging.
// ---------------------------------------------------------------------------
__global__ __launch_bounds__(256,2) void k_sim(
    const short* __restrict__ qc, const short* __restrict__ kc,
    const short* __restrict__ qr, const short* __restrict__ kr,
    const float* __restrict__ csc, const float* __restrict__ fsc,
    const float* __restrict__ s_cls, const float* __restrict__ s_reg,
    float* __restrict__ out)
{
  const int tid  = threadIdx.x;
  const int lane = tid & 63;
  const int w    = tid >> 6;
  const int i0w  = blockIdx.x * 128 + w * 32;
  const int j0   = blockIdx.y * 64;
  const int fr   = lane & 15;
  const int fk   = (lane >> 4) * 8;

  __shared__ __align__(16) short Bsh[2][16][64][8];   // 32 KiB

  float sjc[4], sjf[4];
  #pragma unroll
  for (int js=0;js<4;js++){ sjc[js]=csc[j0+js*16+fr]; sjf[js]=fsc[j0+js*16+fr]; }
  int rowb[2]; float sci[2][4], sfi[2][4];
  #pragma unroll
  for (int ri=0;ri<2;ri++){
    rowb[ri] = i0w + ri*16 + ((lane>>4)<<2);
    #pragma unroll
    for (int r=0;r<4;r++){ sci[ri][r]=csc[rowb[ri]+r]; sfi[ri][r]=fsc[rowb[ri]+r]; }
  }

  f32x4 sim[2][4] = {};

  for (int h=0; h<8; ++h){
    const size_t hb = (size_t)h * NTOK;
    bf16x8 aq[2][4], ar[2][4];
    #pragma unroll
    for (int ri=0;ri<2;ri++)
      #pragma unroll
      for (int kk=0;kk<4;kk++){
        aq[ri][kk] = *(const bf16x8*)&qc[(hb + i0w + ri*16 + fr)*128 + kk*32 + fk];
        ar[ri][kk] = *(const bf16x8*)&qr[(hb + i0w + ri*16 + fr)*128 + kk*32 + fk];
      }
    float iscl[2][4], isrl[2][4];
    #pragma unroll
    for (int ri=0;ri<2;ri++)
      #pragma unroll
      for (int r=0;r<4;r++){
        iscl[ri][r] = 1.0f/s_cls[hb + rowb[ri] + r];
        isrl[ri][r] = 1.0f/s_reg[hb + rowb[ri] + r];
      }
    __syncthreads();
    #pragma unroll
    for (int it=0; it<8; ++it){
      int slot = it*256 + tid;
      int str  = slot >> 10;
      int frag = (slot >> 6) & 15;
      int l    = slot & 63;
      int r    = (frag >> 2)*16 + (l & 15);
      int c    = (frag & 3)*32 + (l >> 4)*8;
      const short* gp = (str ? kr : kc) + (hb + j0 + r)*128 + c;
      *(bf16x8*)&Bsh[str][frag][l][0] = *(const bf16x8*)gp;
    }
    __syncthreads();
    #pragma unroll
    for (int js=0; js<4; ++js){
      bf16x8 bc[4], br[4];
      #pragma unroll
      for (int kk=0;kk<4;kk++){
        bc[kk] = *(const bf16x8*)&Bsh[0][js*4+kk][lane][0];
        br[kk] = *(const bf16x8*)&Bsh[1][js*4+kk][lane][0];
      }
      #pragma unroll
      for (int ri=0;ri<2;ri++){
        f32x4 Sc = {}; f32x4 Sr = {};
        #pragma unroll
        for (int kk=0;kk<4;kk++){
          Sc = MFMA16(aq[ri][kk], bc[kk], Sc);
          Sr = MFMA16(ar[ri][kk], br[kk], Sr);
        }
        #pragma unroll
        for (int r=0;r<4;r++){
          float ec = (sjc[js] > sci[ri][r]-0.1f) ? __expf(Sc[r]*(25.0f*sjc[js])) : 1.0f;
          float er = (sjf[js] > sfi[ri][r]-0.1f) ? __expf(Sr[r]*(25.0f*sjf[js])) : 1.0f;
          sim[ri][js][r] += ec*iscl[ri][r] + er*isrl[ri][r];
        }
      }
    }
  }
  #pragma unroll
  for (int ri=0;ri<2;ri++)
    #pragma unroll
    for (int js=0;js<4;js++)
      #pragma unroll
      for (int r=0;r<4;r++)
        out[4194304ull + (size_t)(rowb[ri]+r)*2048 + j0 + js*16 + fr]
            = sim[ri][js][r] * 0.0625f;
}

// ---------------------------------------------------------------------------
// Kernel 5b: raw = Vn . Vn^T over full C=1024; mask = raw>6.
// ---------------------------------------------------------------------------
__global__ __launch_bounds__(256,4) void k_raw(
    const short* __restrict__ vn, unsigned char* __restrict__ mask)
{
  const int tid  = threadIdx.x;
  const int lane = tid & 63;
  const int w    = tid >> 6;
  const int i0w  = blockIdx.x * 128 + w * 32;
  const int j0   = blockIdx.y * 64;
  const int fr   = lane & 15;
  const int fk   = (lane >> 4) * 8;

  __shared__ __align__(16) short Bsh[16][64][8];   // 16 KiB

  f32x4 raw[2][4] = {};

  for (int cc=0; cc<8; ++cc){
    const size_t hb = (size_t)cc * NTOK;
    bf16x8 av[2][4];
    #pragma unroll
    for (int ri=0;ri<2;ri++)
      #pragma unroll
      for (int kk=0;kk<4;kk++)
        av[ri][kk] = *(const bf16x8*)&vn[(hb + i0w + ri*16 + fr)*128 + kk*32 + fk];
    __syncthreads();
    #pragma unroll
    for (int it=0; it<4; ++it){
      int slot = it*256 + tid;
      int frag = (slot >> 6) & 15;
      int l    = slot & 63;
      int r    = (frag >> 2)*16 + (l & 15);
      int c    = (frag & 3)*32 + (l >> 4)*8;
      *(bf16x8*)&Bsh[frag][l][0] = *(const bf16x8*)&vn[(hb + j0 + r)*128 + c];
    }
    __syncthreads();
    #pragma unroll
    for (int js=0; js<4; ++js){
      bf16x8 bv[4];
      #pragma unroll
      for (int kk=0;kk<4;kk++) bv[kk] = *(const bf16x8*)&Bsh[js*4+kk][lane][0];
      #pragma unroll
      for (int ri=0;ri<2;ri++)
        #pragma unroll
        for (int kk=0;kk<4;kk++)
          raw[ri][js] = MFMA16(av[ri][kk], bv[kk], raw[ri][js]);
    }
  }
  const int rb0 = i0w + ((lane>>4)<<2);
  #pragma unroll
  for (int ri=0;ri<2;ri++)
    #pragma unroll
    for (int js=0;js<4;js++)
      #pragma unroll
      for (int r=0;r<4;r++)
        mask[(size_t)(rb0 + ri*16 + r)*2048 + j0 + js*16 + fr]
            = raw[ri][js][r] > 6.0f ? 1 : 0;
}

// ---------------------------------------------------------------------------
// Kernel 6: final masked renorm (in place on sim half of out).
// ---------------------------------------------------------------------------
__global__ __launch_bounds__(256,4) void k_final(
    float* __restrict__ out, const unsigned char* __restrict__ mask)
{
  int row  = blockIdx.x*4 + (threadIdx.x>>6);
  int lane = threadIdx.x & 63;
  float* sr = out + 4194304ull + (size_t)row*2048;
  const unsigned char* mr = mask + (size_t)row*2048;
  float v[32];
  float sum2 = 0.0f;
  #pragma unroll
  for (int c=0;c<32;c++){
    float e = __expf(sr[c*64 + lane]);
    v[c] = (mr[c*64 + lane] != 0) ? e : 0.0f;
    sum2 += v[c];
  }
  #pragma unroll
  for (int m=1;m<64;m<<=1) sum2 += __shfl_xor(sum2, m);
  float inv = 1.0f / sum2;
  #pragma unroll
  for (int c=0;c<32;c++) sr[c*64 + lane] = v[c]*inv;
}

// ---------------------------------------------------------------------------
extern "C" void kernel_launch(void* const* d_in, const int* in_sizes, int n_in,
                              void* d_out, int out_size, void* d_ws, size_t ws_size,
                              hipStream_t stream)
{
  const float* xcls = (const float*)d_in[0];
  const float* xreg = (const float*)d_in[1];
  const float* csc  = (const float*)d_in[2];
  const float* fsc  = (const float*)d_in[3];
  const float* Wc   = (const float*)d_in[4];
  const float* Wr   = (const float*)d_in[5];
  float* out = (float*)d_out;

  char* ws = (char*)d_ws;
  // Layout:
  //  [0, 41.94MB)  tmp f32 (live k_qkv->k_norm); later overlaid by
  //                 mask @0 (4MB), s_cls/s_reg @4MB (128KB), Up @4MB+128K (33.6MB)
  //  [41.94MB, +28MB) bf16 buffers qc..vT (live from k_norm on); BEFORE k_norm
  //                 this region holds the cvt bf16 inputs (18MB, dead after k_qkv)
  float* tmp          = (float*)ws;
  unsigned char* mask = (unsigned char*)ws;
  char* accbase       = ws + 4u*1024*1024;
  float* s_cls        = (float*)(accbase);
  float* s_reg        = (float*)(accbase + 65536);
  float* Up           = (float*)(accbase + 131072);   // 4 x 8.39MB partials
  short* qc = (short*)(ws + 41943040ull);
  short* kc = qc + 2097152;
  short* qr = kc + 2097152;
  short* kr = qr + 2097152;
  short* vn = kr + 2097152;
  short* vb = vn + 2097152;
  short* vT = vb + 2097152;
  // cvt buffers overlay qc..vT (dead once k_qkv completes)
  short* xbc = (short*)(ws + 41943040ull);
  short* xbr = xbc + 2097152;
  short* wbc = xbr + 2097152;           // 3145728 shorts
  short* wbr = wbc + 3145728;

  k_cvt  <<<4608,        256, 0, stream>>>(xcls, xreg, Wc, Wr, xbc, xbr, wbc, wbr);
  k_qkv  <<<640,         256, 0, stream>>>(xbc, xbr, wbc, wbr, tmp);
  k_norm <<<20480,       256, 0, stream>>>(tmp, out, qc, kc, qr, kr, vn, vb);
  k_vT   <<<512,         256, 0, stream>>>(vb, vT);
  hipMemsetAsync(accbase, 0, 131072, stream);   // zero s_cls/s_reg only
  k_attn <<<512,         256, 0, stream>>>(qc, kc, qr, kr, vT, csc, fsc,
                                           s_cls, s_reg, Up);
  k_attn_fin <<<4096,    256, 0, stream>>>(Up, s_cls, s_reg, out);
  k_raw  <<<dim3(16,32), 256, 0, stream>>>(vn, mask);
  k_sim  <<<dim3(16,32), 256, 0, stream>>>(qc, kc, qr, kr, csc, fsc, s_cls, s_reg, out);
  k_final<<<512,         256, 0, stream>>>(out, mask);
}